// Round 2
// baseline (36268.079 us; speedup 1.0000x reference)
//
#include <hip/hip_runtime.h>
#include <hip/hip_bf16.h>
#include <hip/hip_cooperative_groups.h>
#include <math.h>

namespace cg = cooperative_groups;

// Problem constants
#define SL 256
#define BS 64
#define DI 1024
#define HH 512
#define TT 17
#define NR (SL*BS)        // 16384 rows
#define G4 (4*HH)         // 2048 gates
#define C2 (2*HH)         // 1024 channels

#define BT 16             // batches per coop block
#define UT 8              // hidden units per coop block (32 gate-cols)

__device__ __forceinline__ float sigm(float x) { return 1.f / (1.f + expf(-x)); }

// ---------------------------------------------------------------------------
// Pack w_hh (2048x512, row=gate col=k) -> Wpack [64 hg][512 k][32 (g*8+uu)]
// so each coop block's weight slice is contiguous (64 KB) and k-loop loads
// are full 128B cache lines.
// ---------------------------------------------------------------------------
__global__ __launch_bounds__(256) void pack_whh(const float* __restrict__ whh,
                                                float* __restrict__ wp)
{
    __shared__ float tile[8][513];
    const int hg = blockIdx.x >> 2;   // 0..63
    const int g  = blockIdx.x & 3;    // 0..3
    const int tid = threadIdx.x;
    for (int idx = tid; idx < 8 * 512; idx += 256) {
        const int uu = idx >> 9, k = idx & 511;
        tile[uu][k] = whh[(size_t)(g * 512 + hg * 8 + uu) * HH + k];
    }
    __syncthreads();
    for (int idx = tid; idx < 8 * 512; idx += 256) {
        const int k = idx >> 3, uu = idx & 7;
        wp[(size_t)hg * 16384 + k * 32 + g * 8 + uu] = tile[uu][k];
    }
}

// ---------------------------------------------------------------------------
// xg = X(16384x1024) @ W^T(1024x2048) + b1 + b2   (fp32, 128x128x16 tiles)
// ---------------------------------------------------------------------------
__global__ __launch_bounds__(256) void gemm_xg(
    const float* __restrict__ A,    // [16384][1024]
    const float* __restrict__ W,    // [2048][1024]
    const float* __restrict__ b1,
    const float* __restrict__ b2,
    float* __restrict__ C)          // [16384][2048]
{
    __shared__ float As[16][128];
    __shared__ float Bs[16][128];
    const int tid = threadIdx.x;
    const int m0 = blockIdx.x * 128;
    const int n0 = blockIdx.y * 128;
    const int tm = tid >> 4;
    const int tn = tid & 15;
    const int lr = tid >> 2;
    const int lc = (tid & 3) * 4;

    float acc[8][8];
    #pragma unroll
    for (int i = 0; i < 8; i++)
        #pragma unroll
        for (int j = 0; j < 8; j++) acc[i][j] = 0.f;

    for (int kt = 0; kt < DI; kt += 16) {
        #pragma unroll
        for (int p = 0; p < 2; p++) {
            float4 v = *(const float4*)(A + (size_t)(m0 + p * 64 + lr) * DI + kt + lc);
            As[lc + 0][p * 64 + lr] = v.x;
            As[lc + 1][p * 64 + lr] = v.y;
            As[lc + 2][p * 64 + lr] = v.z;
            As[lc + 3][p * 64 + lr] = v.w;
            float4 w = *(const float4*)(W + (size_t)(n0 + p * 64 + lr) * DI + kt + lc);
            Bs[lc + 0][p * 64 + lr] = w.x;
            Bs[lc + 1][p * 64 + lr] = w.y;
            Bs[lc + 2][p * 64 + lr] = w.z;
            Bs[lc + 3][p * 64 + lr] = w.w;
        }
        __syncthreads();
        #pragma unroll
        for (int kk = 0; kk < 16; kk++) {
            float4 a0 = *(const float4*)&As[kk][tm * 8];
            float4 a1 = *(const float4*)&As[kk][tm * 8 + 4];
            float4 bv0 = *(const float4*)&Bs[kk][tn * 8];
            float4 bv1 = *(const float4*)&Bs[kk][tn * 8 + 4];
            float a[8] = {a0.x, a0.y, a0.z, a0.w, a1.x, a1.y, a1.z, a1.w};
            float b[8] = {bv0.x, bv0.y, bv0.z, bv0.w, bv1.x, bv1.y, bv1.z, bv1.w};
            #pragma unroll
            for (int i = 0; i < 8; i++)
                #pragma unroll
                for (int j = 0; j < 8; j++)
                    acc[i][j] = fmaf(a[i], b[j], acc[i][j]);
        }
        __syncthreads();
    }
    #pragma unroll
    for (int i = 0; i < 8; i++) {
        const int m = m0 + tm * 8 + i;
        float* Crow = C + (size_t)m * G4 + n0 + tn * 8;
        #pragma unroll
        for (int j = 0; j < 8; j++) {
            const int n = n0 + tn * 8 + j;
            Crow[j] = acc[i][j] + b1[n] + b2[n];
        }
    }
}

// ---------------------------------------------------------------------------
// Cooperative persistent LSTM: 256 blocks x 512 threads, one dir per launch.
// Block = (bgroup of 16 batches) x (hgroup of 8 hidden units -> 32 gate cols).
// Per step: gates = xg[t] + H @ Wslice ; local c/h update ; grid.sync().
// thread = (b 0..15, q 0..7 float4 col-chunk, ks 0..3 k-slice of 128)
// ---------------------------------------------------------------------------
__global__ __launch_bounds__(512) void lstm_coop(
    const float* __restrict__ xg,    // [256][64][2048]
    const float* __restrict__ wp,    // [64][512][32] packed
    float* __restrict__ Hbuf,        // [2][512][64]
    float* __restrict__ out,         // [SL*BS][1024]
    int reverse, int col_off)
{
    cg::grid_group grid = cg::this_grid();
    __shared__ float h_lds[512][BT];        // 32 KB  [k][b]
    __shared__ float part[3][BT][8][4];     //  6 KB  k-split partials
    __shared__ float g_lds[BT][32];         //  2 KB  reduced gate preacts

    const int tid = threadIdx.x;
    const int bgroup = blockIdx.x & 3;
    const int hgroup = blockIdx.x >> 2;
    const int B0 = bgroup * BT;
    const int U0 = hgroup * UT;

    const int b_loc = tid >> 5;          // 0..15
    const int q     = (tid >> 2) & 7;    // 0..7
    const int ks    = tid & 3;           // 0..3
    const int g     = q >> 1;            // gate 0..3
    const int uhalf = q & 1;
    const int col_in_xg = g * 512 + U0 + uhalf * 4;
    const float* wslice = wp + (size_t)hgroup * 16384;

    float c = 0.f;   // threads tid<128 own state for (b=tid>>3, uu=tid&7)

    for (int step = 0; step < SL; ++step) {
        const int t = reverse ? (SL - 1 - step) : step;
        float4 acc;
        if (ks == 0) acc = *(const float4*)(xg + (size_t)(t * BS + B0 + b_loc) * G4 + col_in_xg);
        else { acc.x = 0.f; acc.y = 0.f; acc.z = 0.f; acc.w = 0.f; }

        if (step > 0) {
            const float* hsrc = Hbuf + ((step + 1) & 1) * (512 * 64);
            #pragma unroll
            for (int i = 0; i < 4; i++) {
                const int flat = i * 512 + tid;          // 2048 float4s
                const int k = flat >> 2, bq = flat & 3;
                *(float4*)&h_lds[k][bq * 4] = *(const float4*)(hsrc + k * 64 + B0 + bq * 4);
            }
            __syncthreads();
            const int k0 = ks * 128;
            #pragma unroll 8
            for (int kk = 0; kk < 128; ++kk) {
                const int k = k0 + kk;
                const float4 w = *(const float4*)(wslice + (size_t)k * 32 + q * 4);
                const float h = h_lds[k][b_loc];
                acc.x = fmaf(h, w.x, acc.x);
                acc.y = fmaf(h, w.y, acc.y);
                acc.z = fmaf(h, w.z, acc.z);
                acc.w = fmaf(h, w.w, acc.w);
            }
        }

        // k-split reduction
        if (ks > 0) *(float4*)&part[ks - 1][b_loc][q][0] = acc;
        __syncthreads();
        if (ks == 0) {
            #pragma unroll
            for (int r = 0; r < 3; r++) {
                const float4 p = *(const float4*)&part[r][b_loc][q][0];
                acc.x += p.x; acc.y += p.y; acc.z += p.z; acc.w += p.w;
            }
            *(float4*)&g_lds[b_loc][q * 4] = acc;   // col = g*8 + uhalf*4 + e
        }
        __syncthreads();

        if (tid < BT * 8) {
            const int b = tid >> 3, uu = tid & 7;
            const float ig = sigm(g_lds[b][uu]);
            const float fg = sigm(g_lds[b][8 + uu]);
            const float gg = tanhf(g_lds[b][16 + uu]);
            const float og = sigm(g_lds[b][24 + uu]);
            c = fg * c + ig * gg;
            const float h = og * tanhf(c);
            Hbuf[(step & 1) * (512 * 64) + (U0 + uu) * 64 + B0 + b] = h;
            out[(size_t)(t * BS + B0 + b) * C2 + col_off + U0 + uu] = h;
        }
        grid.sync();
    }
}

// ---------------------------------------------------------------------------
// BatchNorm stats: one block per channel (two-pass mean/var)
// ---------------------------------------------------------------------------
__global__ __launch_bounds__(256) void bn_stats(
    const float* __restrict__ X, float* __restrict__ mean, float* __restrict__ istd)
{
    const int ch = blockIdx.x, tid = threadIdx.x;
    __shared__ float red[256];
    float s = 0.f;
    for (int r = tid; r < NR; r += 256) s += X[(size_t)r * C2 + ch];
    red[tid] = s; __syncthreads();
    for (int o = 128; o; o >>= 1) { if (tid < o) red[tid] += red[tid + o]; __syncthreads(); }
    const float mu = red[0] * (1.f / NR);
    __syncthreads();
    float v = 0.f;
    for (int r = tid; r < NR; r += 256) { const float d = X[(size_t)r * C2 + ch] - mu; v = fmaf(d, d, v); }
    red[tid] = v; __syncthreads();
    for (int o = 128; o; o >>= 1) { if (tid < o) red[tid] += red[tid + o]; __syncthreads(); }
    if (tid == 0) { mean[ch] = mu; istd[ch] = rsqrtf(red[0] * (1.f / NR) + 1e-5f); }
}

// ---------------------------------------------------------------------------
// Fold BN into linear
// ---------------------------------------------------------------------------
__global__ void fold_lin(const float* __restrict__ lin_w, const float* __restrict__ lin_b,
                         const float* __restrict__ gamma, const float* __restrict__ beta,
                         const float* __restrict__ mean, const float* __restrict__ istd,
                         float* __restrict__ Wf, float* __restrict__ ct)
{
    const int t = blockIdx.x, tid = threadIdx.x;
    __shared__ float red[256];
    float acc = 0.f;
    for (int cc = tid; cc < C2; cc += 256) {
        const float w = lin_w[t * C2 + cc];
        const float g = gamma[cc] * istd[cc];
        Wf[t * C2 + cc] = w * g;
        acc = fmaf(beta[cc] - mean[cc] * g, w, acc);
    }
    red[tid] = acc; __syncthreads();
    for (int o = 128; o; o >>= 1) { if (tid < o) red[tid] += red[tid + o]; __syncthreads(); }
    if (tid == 0) ct[t] = red[0] + lin_b[t];
}

// ---------------------------------------------------------------------------
// Emission logits E[b][s][t]  (wave per row)
// ---------------------------------------------------------------------------
__global__ __launch_bounds__(256) void emit_logits(
    const float* __restrict__ X, const float* __restrict__ Wf,
    const float* __restrict__ ct, float* __restrict__ E)
{
    const int r = blockIdx.x * 4 + (threadIdx.x >> 6);
    const int lane = threadIdx.x & 63;
    const float* xr = X + (size_t)r * C2;
    float acc[TT];
    #pragma unroll
    for (int t = 0; t < TT; t++) acc[t] = 0.f;
    for (int i = 0; i < C2 / 64; i++) {
        const int cc = i * 64 + lane;
        const float xv = xr[cc];
        #pragma unroll
        for (int t = 0; t < TT; t++) acc[t] = fmaf(xv, Wf[t * C2 + cc], acc[t]);
    }
    #pragma unroll
    for (int t = 0; t < TT; t++)
        for (int off = 32; off; off >>= 1) acc[t] += __shfl_xor(acc[t], off);
    if (lane == 0) {
        const int b = r & (BS - 1), s = r >> 6;
        float* Er = E + ((size_t)b * SL + s) * TT;
        #pragma unroll
        for (int t = 0; t < TT; t++) Er[t] = acc[t] + ct[t];
    }
}

// ---------------------------------------------------------------------------
// CRF log-likelihood per batch element
// ---------------------------------------------------------------------------
__global__ __launch_bounds__(64) void crf_llh(
    const float* __restrict__ E, const int* __restrict__ mask,
    const int* __restrict__ labels, const float* __restrict__ startv,
    const float* __restrict__ endv, const float* __restrict__ trans,
    float* __restrict__ res)
{
    const int b = blockIdx.x, lane = threadIdx.x;
    __shared__ float tr[TT][TT];
    for (int i = lane; i < TT * TT; i += 64) tr[i / TT][i % TT] = trans[i];
    __syncthreads();
    const float* Eb = E + (size_t)b * SL * TT;
    const int j = (lane < TT) ? lane : 0;

    float alpha = -1e30f;
    if (lane < TT) alpha = startv[lane] + Eb[lane];

    float numacc = 0.f; int len = 0;
    for (int t = lane; t < SL; t += 64) {
        const int mt = mask[t * BS + b];
        len += (mt != 0);
        if (t >= 1 && mt) {
            const int yp = labels[(t - 1) * BS + b];
            const int yt = labels[t * BS + b];
            numacc += tr[yp][yt] + Eb[t * TT + yt];
        }
    }
    for (int off = 32; off; off >>= 1) {
        numacc += __shfl_xor(numacc, off);
        len += __shfl_xor(len, off);
    }

    for (int t = 1; t < SL; ++t) {
        const int mt = mask[t * BS + b];
        if (mt) {
            float av[TT];
            #pragma unroll
            for (int i = 0; i < TT; i++) av[i] = __shfl(alpha, i);
            const float e = (lane < TT) ? Eb[t * TT + lane] : 0.f;
            float mx = -1e30f;
            #pragma unroll
            for (int i = 0; i < TT; i++) mx = fmaxf(mx, av[i] + tr[i][j]);
            float s = 0.f;
            #pragma unroll
            for (int i = 0; i < TT; i++) s += expf(av[i] + tr[i][j] - mx);
            const float nxt = mx + logf(s) + e;
            if (lane < TT) alpha = nxt;
        }
    }
    float v = (lane < TT) ? alpha + endv[lane] : -1e30f;
    float mx = v;
    for (int off = 32; off; off >>= 1) mx = fmaxf(mx, __shfl_xor(mx, off));
    float se = (lane < TT) ? expf(v - mx) : 0.f;
    for (int off = 32; off; off >>= 1) se += __shfl_xor(se, off);
    const float Z = mx + logf(se);

    if (lane == 0) {
        const int y0 = labels[b];
        float num = startv[y0] + Eb[y0] + numacc;
        const int last = len - 1;
        const int yl = labels[last * BS + b];
        num += endv[yl];
        res[b] = num - Z;
    }
}

__global__ __launch_bounds__(64) void loss_reduce(const float* __restrict__ res, float* __restrict__ out)
{
    const int lane = threadIdx.x;
    float v = res[lane];
    for (int off = 32; off; off >>= 1) v += __shfl_xor(v, off);
    if (lane == 0) out[0] = -v;
}

// ---------------------------------------------------------------------------
// Viterbi per batch element
// ---------------------------------------------------------------------------
__global__ __launch_bounds__(64) void viterbi(
    const float* __restrict__ E, const int* __restrict__ mask,
    const float* __restrict__ startv, const float* __restrict__ endv,
    const float* __restrict__ trans, float* __restrict__ preds)
{
    const int b = blockIdx.x, lane = threadIdx.x;
    __shared__ float tr[TT][TT];
    __shared__ unsigned char bp[SL][TT];
    for (int i = lane; i < TT * TT; i += 64) tr[i / TT][i % TT] = trans[i];
    __syncthreads();
    const float* Eb = E + (size_t)b * SL * TT;
    const int j = (lane < TT) ? lane : 0;

    float score = (lane < TT) ? startv[lane] + Eb[lane] : -1e30f;
    for (int t = 1; t < SL; ++t) {
        float av[TT];
        #pragma unroll
        for (int i = 0; i < TT; i++) av[i] = __shfl(score, i);
        float best = -1e30f; int bi = 0;
        #pragma unroll
        for (int i = 0; i < TT; i++) {
            const float cand = av[i] + tr[i][j];
            if (cand > best) { best = cand; bi = i; }
        }
        const int mt = mask[t * BS + b];
        if (lane < TT) {
            bp[t][lane] = (unsigned char)bi;
            if (mt) score = best + Eb[t * TT + lane];
        }
    }
    float v = (lane < TT) ? score + endv[lane] : -1e30f;
    float mx = v;
    for (int off = 32; off; off >>= 1) mx = fmaxf(mx, __shfl_xor(mx, off));
    unsigned long long ball = __ballot(v == mx);
    const int last_tag = __ffsll(ball) - 1;
    __syncthreads();

    if (lane == 0) {
        int tag = last_tag;
        float* pb = preds + (size_t)b * SL;
        for (int t = SL - 1; t >= 1; --t) {
            const int mt = mask[t * BS + b];
            pb[t] = mt ? (float)tag : 0.f;
            if (mt) tag = bp[t][tag];
        }
        pb[0] = mask[b] ? (float)tag : 0.f;
    }
}

// ---------------------------------------------------------------------------
extern "C" void kernel_launch(void* const* d_in, const int* in_sizes, int n_in,
                              void* d_out, int out_size, void* d_ws, size_t ws_size,
                              hipStream_t stream)
{
    const float* word    = (const float*)d_in[0];
    const int*   mask    = (const int*)  d_in[1];
    const int*   labels  = (const int*)  d_in[2];
    const float* w_ih_f  = (const float*)d_in[3];
    const float* w_hh_f  = (const float*)d_in[4];
    const float* b_ih_f  = (const float*)d_in[5];
    const float* b_hh_f  = (const float*)d_in[6];
    const float* w_ih_b  = (const float*)d_in[7];
    const float* w_hh_b  = (const float*)d_in[8];
    const float* b_ih_b  = (const float*)d_in[9];
    const float* b_hh_b  = (const float*)d_in[10];
    const float* gamma   = (const float*)d_in[11];
    const float* beta    = (const float*)d_in[12];
    const float* lin_w   = (const float*)d_in[13];
    const float* lin_b   = (const float*)d_in[14];
    const float* c_start = (const float*)d_in[15];
    const float* c_end   = (const float*)d_in[16];
    const float* c_trans = (const float*)d_in[17];
    float* out = (float*)d_out;
    (void)in_sizes; (void)n_in; (void)out_size; (void)ws_size;

    char* ws = (char*)d_ws;
    size_t off = 0;
    auto alloc = [&](size_t bytes) {
        void* p = ws + off;
        off += (bytes + 255) & ~(size_t)255;
        return p;
    };
    float* XG   = (float*)alloc((size_t)NR * G4 * 4);   // 128 MB (reused f/b)
    float* WP_F = (float*)alloc((size_t)HH * G4 * 4);   // 4 MB packed weights
    float* WP_B = (float*)alloc((size_t)HH * G4 * 4);   // 4 MB
    float* LOUT = (float*)alloc((size_t)NR * C2 * 4);   // 64 MB
    float* HBUF = (float*)alloc((size_t)2 * 512 * 64 * 4); // 256 KB
    float* MEAN = (float*)alloc(C2 * 4);
    float* ISTD = (float*)alloc(C2 * 4);
    float* WF   = (float*)alloc(TT * C2 * 4);
    float* CT   = (float*)alloc(TT * 4);
    float* Ebuf = (float*)alloc((size_t)BS * SL * TT * 4);
    float* RES  = (float*)alloc(BS * 4);
    // total ~202 MB

    pack_whh<<<256, 256, 0, stream>>>(w_hh_f, WP_F);
    pack_whh<<<256, 256, 0, stream>>>(w_hh_b, WP_B);

    // forward direction
    gemm_xg<<<dim3(NR / 128, G4 / 128), 256, 0, stream>>>(word, w_ih_f, b_ih_f, b_hh_f, XG);
    {
        const float* xg_p = XG; const float* wp_p = WP_F; float* hb_p = HBUF; float* out_p = LOUT;
        int rev = 0, co = 0;
        void* args[6] = {(void*)&xg_p, (void*)&wp_p, (void*)&hb_p, (void*)&out_p, (void*)&rev, (void*)&co};
        hipLaunchCooperativeKernel((void*)lstm_coop, dim3(256), dim3(512), args, 0, stream);
    }
    // backward direction (reuses XG)
    gemm_xg<<<dim3(NR / 128, G4 / 128), 256, 0, stream>>>(word, w_ih_b, b_ih_b, b_hh_b, XG);
    {
        const float* xg_p = XG; const float* wp_p = WP_B; float* hb_p = HBUF; float* out_p = LOUT;
        int rev = 1, co = HH;
        void* args[6] = {(void*)&xg_p, (void*)&wp_p, (void*)&hb_p, (void*)&out_p, (void*)&rev, (void*)&co};
        hipLaunchCooperativeKernel((void*)lstm_coop, dim3(256), dim3(512), args, 0, stream);
    }

    bn_stats<<<C2, 256, 0, stream>>>(LOUT, MEAN, ISTD);
    fold_lin<<<TT, 256, 0, stream>>>(lin_w, lin_b, gamma, beta, MEAN, ISTD, WF, CT);
    emit_logits<<<NR / 4, 256, 0, stream>>>(LOUT, WF, CT, Ebuf);

    crf_llh<<<BS, 64, 0, stream>>>(Ebuf, mask, labels, c_start, c_end, c_trans, RES);
    loss_reduce<<<1, 64, 0, stream>>>(RES, out);
    viterbi<<<BS, 64, 0, stream>>>(Ebuf, mask, c_start, c_end, c_trans, out + 1);
}

// Round 3
// 11777.748 us; speedup vs baseline: 3.0794x; 3.0794x over previous
//
#include <hip/hip_runtime.h>
#include <hip/hip_bf16.h>
#include <math.h>

// Problem constants
#define SL 256
#define BS 64
#define DI 1024
#define HH 512
#define TT 17
#define NR (SL*BS)        // 16384 rows
#define G4 (4*HH)         // 2048 gates
#define C2 (2*HH)         // 1024 channels
#define NBLK 256          // blocks per direction in lstm_flag

__device__ __forceinline__ float sigm(float x) { return 1.f / (1.f + expf(-x)); }

// ---------------------------------------------------------------------------
// Pack w_hh (2048x512) -> wp[256 slices][512 k][12] (cols c=g*2+uu, pad 8..11)
// slice s owns h-units {2s, 2s+1}; col c<8: g=c>>1, uu=c&1 -> row g*512+2s+uu
// ---------------------------------------------------------------------------
__global__ __launch_bounds__(256) void pack_whh_v3(const float* __restrict__ whh,
                                                   float* __restrict__ wp)
{
    const int s = blockIdx.x;
    for (int idx = threadIdx.x; idx < 512 * 12; idx += 256) {
        const int k = idx / 12, c = idx % 12;
        float v = 0.f;
        if (c < 8) {
            const int g = c >> 1, uu = c & 1;
            v = whh[(size_t)(g * 512 + 2 * s + uu) * HH + k];
        }
        wp[(size_t)s * 6144 + idx] = v;
    }
}

__global__ __launch_bounds__(512) void init_flags(int* __restrict__ f)
{
    f[blockIdx.x * 512 + threadIdx.x] = 0;   // 256*512 = 2*256*256 ints
}

// ---------------------------------------------------------------------------
// xg = X(16384x1024) @ W^T(1024x2048) + b1 + b2   (fp32, 128x128x16 tiles)
// ---------------------------------------------------------------------------
__global__ __launch_bounds__(256) void gemm_xg(
    const float* __restrict__ A,    // [16384][1024]
    const float* __restrict__ W,    // [2048][1024]
    const float* __restrict__ b1,
    const float* __restrict__ b2,
    float* __restrict__ C)          // [16384][2048]
{
    __shared__ float As[16][128];
    __shared__ float Bs[16][128];
    const int tid = threadIdx.x;
    const int m0 = blockIdx.x * 128;
    const int n0 = blockIdx.y * 128;
    const int tm = tid >> 4;
    const int tn = tid & 15;
    const int lr = tid >> 2;
    const int lc = (tid & 3) * 4;

    float acc[8][8];
    #pragma unroll
    for (int i = 0; i < 8; i++)
        #pragma unroll
        for (int j = 0; j < 8; j++) acc[i][j] = 0.f;

    for (int kt = 0; kt < DI; kt += 16) {
        #pragma unroll
        for (int p = 0; p < 2; p++) {
            float4 v = *(const float4*)(A + (size_t)(m0 + p * 64 + lr) * DI + kt + lc);
            As[lc + 0][p * 64 + lr] = v.x;
            As[lc + 1][p * 64 + lr] = v.y;
            As[lc + 2][p * 64 + lr] = v.z;
            As[lc + 3][p * 64 + lr] = v.w;
            float4 w = *(const float4*)(W + (size_t)(n0 + p * 64 + lr) * DI + kt + lc);
            Bs[lc + 0][p * 64 + lr] = w.x;
            Bs[lc + 1][p * 64 + lr] = w.y;
            Bs[lc + 2][p * 64 + lr] = w.z;
            Bs[lc + 3][p * 64 + lr] = w.w;
        }
        __syncthreads();
        #pragma unroll
        for (int kk = 0; kk < 16; kk++) {
            float4 a0 = *(const float4*)&As[kk][tm * 8];
            float4 a1 = *(const float4*)&As[kk][tm * 8 + 4];
            float4 bv0 = *(const float4*)&Bs[kk][tn * 8];
            float4 bv1 = *(const float4*)&Bs[kk][tn * 8 + 4];
            float a[8] = {a0.x, a0.y, a0.z, a0.w, a1.x, a1.y, a1.z, a1.w};
            float b[8] = {bv0.x, bv0.y, bv0.z, bv0.w, bv1.x, bv1.y, bv1.z, bv1.w};
            #pragma unroll
            for (int i = 0; i < 8; i++)
                #pragma unroll
                for (int j = 0; j < 8; j++)
                    acc[i][j] = fmaf(a[i], b[j], acc[i][j]);
        }
        __syncthreads();
    }
    #pragma unroll
    for (int i = 0; i < 8; i++) {
        const int m = m0 + tm * 8 + i;
        float* Crow = C + (size_t)m * G4 + n0 + tn * 8;
        #pragma unroll
        for (int j = 0; j < 8; j++) {
            const int n = n0 + tn * 8 + j;
            Crow[j] = acc[i][j] + b1[n] + b2[n];
        }
    }
}

// ---------------------------------------------------------------------------
// Flag-pipelined LSTM: 256 blocks x 512 threads, one direction per launch.
// Block s owns h-units {2s,2s+1} (8 gate cols). Weights resident in LDS.
// Per step: stage full H(t-1) [512x64] via agent-scope atomic loads (coherent
// across XCDs, no cache flushes), GEMM (thread tile 8b x 4c, 32 k-slices),
// shfl k-reduce, gate nonlinearity (c-state in regs), publish h via agent
// atomic stores, release flag. Consumers spin on previous step's 256 flags.
// ---------------------------------------------------------------------------
__global__ __launch_bounds__(512) void lstm_flag(
    const float* __restrict__ xg,    // [256][64][2048]
    const float* __restrict__ wp,    // [256][512][12]
    float* __restrict__ Hbuf,        // [2][512][64]
    int* __restrict__ flag,          // [SL][NBLK] for this dir
    float* __restrict__ out,         // [SL*BS][1024]
    int reverse, int col_off)
{
    __shared__ float w_s[512 * 12];              // 24576 B, persistent
    __shared__ float hs[128 * 66];               // 33792 B, reused per chunk
    float* const part = hs;                      // [8][524] overlay (16768 B)
    float* const g_s  = hs + 8 * 524;            // [8][64]  overlay (2048 B)

    const int tid = threadIdx.x;
    const int s   = blockIdx.x;
    const int ks  = tid >> 4;        // 0..31 k-slice
    const int bt  = (tid >> 1) & 7;  // 0..7 batch tile
    const int ct  = tid & 1;         // 0..1 col tile (4 cols each)
    const int wv  = tid >> 6;        // wave 0..7

    // stage weights once (1536 float4)
    {
        const float4* src = (const float4*)(wp + (size_t)s * 6144);
        float4* dst = (float4*)w_s;
        for (int i = tid; i < 1536; i += 512) dst[i] = src[i];
    }

    float cst = 0.f;                  // c-state: tid<128 owns (b=tid&63, uu=tid>>6)
    float4 acc[8];
    float r[16];

    for (int step = 0; step < SL; ++step) {
        const int t = reverse ? (SL - 1 - step) : step;

        if (step > 0) {
            if (tid < NBLK) {
                const int* f = flag + (step - 1) * NBLK + tid;
                while (__hip_atomic_load(f, __ATOMIC_RELAXED, __HIP_MEMORY_SCOPE_AGENT) == 0)
                    __builtin_amdgcn_s_sleep(2);
            }
            __syncthreads();   // all flags seen; also covers initial w_s staging
        }

        #pragma unroll
        for (int i = 0; i < 8; ++i) acc[i] = make_float4(0.f, 0.f, 0.f, 0.f);

        if (step > 0) {
            const float* hsrc = Hbuf + ((step + 1) & 1) * (512 * 64);
            // prefetch chunk 0 (coherent atomic loads; fresh from MALL)
            #pragma unroll
            for (int i = 0; i < 16; ++i) {
                const int fl = i * 512 + tid;
                r[i] = __hip_atomic_load(hsrc + (fl >> 6) * 64 + (fl & 63),
                                         __ATOMIC_RELAXED, __HIP_MEMORY_SCOPE_AGENT);
            }
            for (int kc = 0; kc < 4; ++kc) {
                __syncthreads();                       // prev chunk's compute done
                #pragma unroll
                for (int i = 0; i < 16; ++i) {
                    const int fl = i * 512 + tid;      // kk = fl>>6 (wave-uniform), b = fl&63
                    hs[(fl >> 6) * 66 + (fl & 63)] = r[i];
                }
                __syncthreads();                       // hs ready
                if (kc < 3) {                          // prefetch next chunk DURING compute
                    #pragma unroll
                    for (int i = 0; i < 16; ++i) {
                        const int fl = i * 512 + tid;
                        r[i] = __hip_atomic_load(hsrc + ((kc + 1) * 128 + (fl >> 6)) * 64 + (fl & 63),
                                                 __ATOMIC_RELAXED, __HIP_MEMORY_SCOPE_AGENT);
                    }
                }
                #pragma unroll
                for (int j = 0; j < 4; ++j) {
                    const int kk = ks + 32 * j;        // strided k: spreads banks by ks
                    const int kg = kc * 128 + kk;
                    const float4 w = *(const float4*)&w_s[kg * 12 + ct * 4];
                    const float* hp = &hs[kk * 66 + 8 * bt];
                    const float2 h01 = *(const float2*)(hp + 0);
                    const float2 h23 = *(const float2*)(hp + 2);
                    const float2 h45 = *(const float2*)(hp + 4);
                    const float2 h67 = *(const float2*)(hp + 6);
                    const float hv[8] = {h01.x, h01.y, h23.x, h23.y, h45.x, h45.y, h67.x, h67.y};
                    #pragma unroll
                    for (int i = 0; i < 8; ++i) {
                        acc[i].x = fmaf(hv[i], w.x, acc[i].x);
                        acc[i].y = fmaf(hv[i], w.y, acc[i].y);
                        acc[i].z = fmaf(hv[i], w.z, acc[i].z);
                        acc[i].w = fmaf(hv[i], w.w, acc[i].w);
                    }
                }
            }
            // k-reduce within wave: ks lanes differ by bits 4,5 of tid
            #pragma unroll
            for (int i = 0; i < 8; ++i) {
                acc[i].x += __shfl_xor(acc[i].x, 16);
                acc[i].y += __shfl_xor(acc[i].y, 16);
                acc[i].z += __shfl_xor(acc[i].z, 16);
                acc[i].w += __shfl_xor(acc[i].w, 16);
                acc[i].x += __shfl_xor(acc[i].x, 32);
                acc[i].y += __shfl_xor(acc[i].y, 32);
                acc[i].z += __shfl_xor(acc[i].z, 32);
                acc[i].w += __shfl_xor(acc[i].w, 32);
            }
            __syncthreads();                           // hs reads done; part overlays hs
            if ((tid & 63) < 16) {                     // one ks per wave writes wave-partial
                #pragma unroll
                for (int i = 0; i < 8; ++i)
                    *(float4*)&part[wv * 524 + (8 * bt + i) * 8 + ct * 4] = acc[i];
            }
            __syncthreads();
        }

        // cross-wave reduce + xg: gate idx = tid (512 gates = 64b x 8c)
        {
            const int b = tid >> 3, c = tid & 7;
            const int g = c >> 1, uu = c & 1;
            float v = xg[(size_t)(t * BS + b) * G4 + g * 512 + 2 * s + uu];
            if (step > 0) {
                #pragma unroll
                for (int w = 0; w < 8; ++w) v += part[w * 524 + b * 8 + c];
            }
            g_s[c * 64 + b] = v;
        }
        __syncthreads();

        if (tid < 128) {
            const int b = tid & 63, uu = tid >> 6;
            const float ig = sigm(g_s[(0 + uu) * 64 + b]);
            const float fg = sigm(g_s[(2 + uu) * 64 + b]);
            const float gg = tanhf(g_s[(4 + uu) * 64 + b]);
            const float og = sigm(g_s[(6 + uu) * 64 + b]);
            cst = fg * cst + ig * gg;
            const float h = og * tanhf(cst);
            __hip_atomic_store(Hbuf + (step & 1) * (512 * 64) + (2 * s + uu) * 64 + b, h,
                               __ATOMIC_RELAXED, __HIP_MEMORY_SCOPE_AGENT);
            out[(size_t)(t * BS + b) * C2 + col_off + 2 * s + uu] = h;
        }
        __syncthreads();   // vmcnt(0) drain: h stores visible at coherent point
        if (tid == 0)
            __hip_atomic_store(flag + step * NBLK + s, 1,
                               __ATOMIC_RELEASE, __HIP_MEMORY_SCOPE_AGENT);
    }
}

// ---------------------------------------------------------------------------
// BatchNorm stats: one block per channel (two-pass mean/var)
// ---------------------------------------------------------------------------
__global__ __launch_bounds__(256) void bn_stats(
    const float* __restrict__ X, float* __restrict__ mean, float* __restrict__ istd)
{
    const int ch = blockIdx.x, tid = threadIdx.x;
    __shared__ float red[256];
    float s = 0.f;
    for (int r = tid; r < NR; r += 256) s += X[(size_t)r * C2 + ch];
    red[tid] = s; __syncthreads();
    for (int o = 128; o; o >>= 1) { if (tid < o) red[tid] += red[tid + o]; __syncthreads(); }
    const float mu = red[0] * (1.f / NR);
    __syncthreads();
    float v = 0.f;
    for (int r = tid; r < NR; r += 256) { const float d = X[(size_t)r * C2 + ch] - mu; v = fmaf(d, d, v); }
    red[tid] = v; __syncthreads();
    for (int o = 128; o; o >>= 1) { if (tid < o) red[tid] += red[tid + o]; __syncthreads(); }
    if (tid == 0) { mean[ch] = mu; istd[ch] = rsqrtf(red[0] * (1.f / NR) + 1e-5f); }
}

// ---------------------------------------------------------------------------
// Fold BN into linear
// ---------------------------------------------------------------------------
__global__ void fold_lin(const float* __restrict__ lin_w, const float* __restrict__ lin_b,
                         const float* __restrict__ gamma, const float* __restrict__ beta,
                         const float* __restrict__ mean, const float* __restrict__ istd,
                         float* __restrict__ Wf, float* __restrict__ ct)
{
    const int t = blockIdx.x, tid = threadIdx.x;
    __shared__ float red[256];
    float acc = 0.f;
    for (int cc = tid; cc < C2; cc += 256) {
        const float w = lin_w[t * C2 + cc];
        const float g = gamma[cc] * istd[cc];
        Wf[t * C2 + cc] = w * g;
        acc = fmaf(beta[cc] - mean[cc] * g, w, acc);
    }
    red[tid] = acc; __syncthreads();
    for (int o = 128; o; o >>= 1) { if (tid < o) red[tid] += red[tid + o]; __syncthreads(); }
    if (tid == 0) ct[t] = red[0] + lin_b[t];
}

// ---------------------------------------------------------------------------
// Emission logits E[b][s][t]  (wave per row)
// ---------------------------------------------------------------------------
__global__ __launch_bounds__(256) void emit_logits(
    const float* __restrict__ X, const float* __restrict__ Wf,
    const float* __restrict__ ct, float* __restrict__ E)
{
    const int r = blockIdx.x * 4 + (threadIdx.x >> 6);
    const int lane = threadIdx.x & 63;
    const float* xr = X + (size_t)r * C2;
    float acc[TT];
    #pragma unroll
    for (int t = 0; t < TT; t++) acc[t] = 0.f;
    for (int i = 0; i < C2 / 64; i++) {
        const int cc = i * 64 + lane;
        const float xv = xr[cc];
        #pragma unroll
        for (int t = 0; t < TT; t++) acc[t] = fmaf(xv, Wf[t * C2 + cc], acc[t]);
    }
    #pragma unroll
    for (int t = 0; t < TT; t++)
        for (int off = 32; off; off >>= 1) acc[t] += __shfl_xor(acc[t], off);
    if (lane == 0) {
        const int b = r & (BS - 1), s = r >> 6;
        float* Er = E + ((size_t)b * SL + s) * TT;
        #pragma unroll
        for (int t = 0; t < TT; t++) Er[t] = acc[t] + ct[t];
    }
}

// ---------------------------------------------------------------------------
// CRF log-likelihood per batch element
// ---------------------------------------------------------------------------
__global__ __launch_bounds__(64) void crf_llh(
    const float* __restrict__ E, const int* __restrict__ mask,
    const int* __restrict__ labels, const float* __restrict__ startv,
    const float* __restrict__ endv, const float* __restrict__ trans,
    float* __restrict__ res)
{
    const int b = blockIdx.x, lane = threadIdx.x;
    __shared__ float tr[TT][TT];
    for (int i = lane; i < TT * TT; i += 64) tr[i / TT][i % TT] = trans[i];
    __syncthreads();
    const float* Eb = E + (size_t)b * SL * TT;
    const int j = (lane < TT) ? lane : 0;

    float alpha = -1e30f;
    if (lane < TT) alpha = startv[lane] + Eb[lane];

    float numacc = 0.f; int len = 0;
    for (int t = lane; t < SL; t += 64) {
        const int mt = mask[t * BS + b];
        len += (mt != 0);
        if (t >= 1 && mt) {
            const int yp = labels[(t - 1) * BS + b];
            const int yt = labels[t * BS + b];
            numacc += tr[yp][yt] + Eb[t * TT + yt];
        }
    }
    for (int off = 32; off; off >>= 1) {
        numacc += __shfl_xor(numacc, off);
        len += __shfl_xor(len, off);
    }

    for (int t = 1; t < SL; ++t) {
        const int mt = mask[t * BS + b];
        if (mt) {
            float av[TT];
            #pragma unroll
            for (int i = 0; i < TT; i++) av[i] = __shfl(alpha, i);
            const float e = (lane < TT) ? Eb[t * TT + lane] : 0.f;
            float mx = -1e30f;
            #pragma unroll
            for (int i = 0; i < TT; i++) mx = fmaxf(mx, av[i] + tr[i][j]);
            float s = 0.f;
            #pragma unroll
            for (int i = 0; i < TT; i++) s += expf(av[i] + tr[i][j] - mx);
            const float nxt = mx + logf(s) + e;
            if (lane < TT) alpha = nxt;
        }
    }
    float v = (lane < TT) ? alpha + endv[lane] : -1e30f;
    float mx = v;
    for (int off = 32; off; off >>= 1) mx = fmaxf(mx, __shfl_xor(mx, off));
    float se = (lane < TT) ? expf(v - mx) : 0.f;
    for (int off = 32; off; off >>= 1) se += __shfl_xor(se, off);
    const float Z = mx + logf(se);

    if (lane == 0) {
        const int y0 = labels[b];
        float num = startv[y0] + Eb[y0] + numacc;
        const int last = len - 1;
        const int yl = labels[last * BS + b];
        num += endv[yl];
        res[b] = num - Z;
    }
}

__global__ __launch_bounds__(64) void loss_reduce(const float* __restrict__ res, float* __restrict__ out)
{
    const int lane = threadIdx.x;
    float v = res[lane];
    for (int off = 32; off; off >>= 1) v += __shfl_xor(v, off);
    if (lane == 0) out[0] = -v;
}

// ---------------------------------------------------------------------------
// Viterbi per batch element
// ---------------------------------------------------------------------------
__global__ __launch_bounds__(64) void viterbi(
    const float* __restrict__ E, const int* __restrict__ mask,
    const float* __restrict__ startv, const float* __restrict__ endv,
    const float* __restrict__ trans, float* __restrict__ preds)
{
    const int b = blockIdx.x, lane = threadIdx.x;
    __shared__ float tr[TT][TT];
    __shared__ unsigned char bp[SL][TT];
    for (int i = lane; i < TT * TT; i += 64) tr[i / TT][i % TT] = trans[i];
    __syncthreads();
    const float* Eb = E + (size_t)b * SL * TT;
    const int j = (lane < TT) ? lane : 0;

    float score = (lane < TT) ? startv[lane] + Eb[lane] : -1e30f;
    for (int t = 1; t < SL; ++t) {
        float av[TT];
        #pragma unroll
        for (int i = 0; i < TT; i++) av[i] = __shfl(score, i);
        float best = -1e30f; int bi = 0;
        #pragma unroll
        for (int i = 0; i < TT; i++) {
            const float cand = av[i] + tr[i][j];
            if (cand > best) { best = cand; bi = i; }
        }
        const int mt = mask[t * BS + b];
        if (lane < TT) {
            bp[t][lane] = (unsigned char)bi;
            if (mt) score = best + Eb[t * TT + lane];
        }
    }
    float v = (lane < TT) ? score + endv[lane] : -1e30f;
    float mx = v;
    for (int off = 32; off; off >>= 1) mx = fmaxf(mx, __shfl_xor(mx, off));
    unsigned long long ball = __ballot(v == mx);
    const int last_tag = __ffsll(ball) - 1;
    __syncthreads();

    if (lane == 0) {
        int tag = last_tag;
        float* pb = preds + (size_t)b * SL;
        for (int t = SL - 1; t >= 1; --t) {
            const int mt = mask[t * BS + b];
            pb[t] = mt ? (float)tag : 0.f;
            if (mt) tag = bp[t][tag];
        }
        pb[0] = mask[b] ? (float)tag : 0.f;
    }
}

// ---------------------------------------------------------------------------
extern "C" void kernel_launch(void* const* d_in, const int* in_sizes, int n_in,
                              void* d_out, int out_size, void* d_ws, size_t ws_size,
                              hipStream_t stream)
{
    const float* word    = (const float*)d_in[0];
    const int*   mask    = (const int*)  d_in[1];
    const int*   labels  = (const int*)  d_in[2];
    const float* w_ih_f  = (const float*)d_in[3];
    const float* w_hh_f  = (const float*)d_in[4];
    const float* b_ih_f  = (const float*)d_in[5];
    const float* b_hh_f  = (const float*)d_in[6];
    const float* w_ih_b  = (const float*)d_in[7];
    const float* w_hh_b  = (const float*)d_in[8];
    const float* b_ih_b  = (const float*)d_in[9];
    const float* b_hh_b  = (const float*)d_in[10];
    const float* gamma   = (const float*)d_in[11];
    const float* beta    = (const float*)d_in[12];
    const float* lin_w   = (const float*)d_in[13];
    const float* lin_b   = (const float*)d_in[14];
    const float* c_start = (const float*)d_in[15];
    const float* c_end   = (const float*)d_in[16];
    const float* c_trans = (const float*)d_in[17];
    float* out = (float*)d_out;
    (void)in_sizes; (void)n_in; (void)out_size; (void)ws_size;

    char* ws = (char*)d_ws;
    size_t off = 0;
    auto alloc = [&](size_t bytes) {
        void* p = ws + off;
        off += (bytes + 255) & ~(size_t)255;
        return p;
    };
    float* XG    = (float*)alloc((size_t)NR * G4 * 4);          // 128 MB (reused f/b)
    float* WPK_F = (float*)alloc((size_t)256 * 6144 * 4);       // 6.3 MB packed
    float* WPK_B = (float*)alloc((size_t)256 * 6144 * 4);       // 6.3 MB
    float* LOUT  = (float*)alloc((size_t)NR * C2 * 4);          // 64 MB
    float* HBUF  = (float*)alloc((size_t)2 * 512 * 64 * 4);     // 256 KB
    int*   FLAGS = (int*)  alloc((size_t)2 * SL * NBLK * 4);    // 512 KB
    float* MEAN  = (float*)alloc(C2 * 4);
    float* ISTD  = (float*)alloc(C2 * 4);
    float* WF    = (float*)alloc(TT * C2 * 4);
    float* CT    = (float*)alloc(TT * 4);
    float* Ebuf  = (float*)alloc((size_t)BS * SL * TT * 4);
    float* RES   = (float*)alloc(BS * 4);
    // total ~207 MB

    init_flags<<<256, 512, 0, stream>>>(FLAGS);
    pack_whh_v3<<<256, 256, 0, stream>>>(w_hh_f, WPK_F);
    pack_whh_v3<<<256, 256, 0, stream>>>(w_hh_b, WPK_B);

    // forward direction
    gemm_xg<<<dim3(NR / 128, G4 / 128), 256, 0, stream>>>(word, w_ih_f, b_ih_f, b_hh_f, XG);
    lstm_flag<<<NBLK, 512, 0, stream>>>(XG, WPK_F, HBUF, FLAGS, LOUT, 0, 0);
    // backward direction (reuses XG; stream order serializes)
    gemm_xg<<<dim3(NR / 128, G4 / 128), 256, 0, stream>>>(word, w_ih_b, b_ih_b, b_hh_b, XG);
    lstm_flag<<<NBLK, 512, 0, stream>>>(XG, WPK_B, HBUF, FLAGS + SL * NBLK, LOUT, 1, HH);

    bn_stats<<<C2, 256, 0, stream>>>(LOUT, MEAN, ISTD);
    fold_lin<<<TT, 256, 0, stream>>>(lin_w, lin_b, gamma, beta, MEAN, ISTD, WF, CT);
    emit_logits<<<NR / 4, 256, 0, stream>>>(LOUT, WF, CT, Ebuf);

    crf_llh<<<BS, 64, 0, stream>>>(Ebuf, mask, labels, c_start, c_end, c_trans, RES);
    loss_reduce<<<1, 64, 0, stream>>>(RES, out);
    viterbi<<<BS, 64, 0, stream>>>(Ebuf, mask, c_start, c_end, c_trans, out + 1);
}

// Round 4
// 10990.760 us; speedup vs baseline: 3.2999x; 1.0716x over previous
//
#include <hip/hip_runtime.h>
#include <hip/hip_bf16.h>
#include <math.h>

// Problem constants
#define SL 256
#define BS 64
#define DI 1024
#define HH 512
#define TT 17
#define NR (SL*BS)        // 16384 rows
#define G4 (4*HH)         // 2048 gates
#define C2 (2*HH)         // 1024 channels
#define NBLK 256          // blocks per direction in lstm_flag

__device__ __forceinline__ float sigm(float x) { return 1.f / (1.f + expf(-x)); }

// Coherent (L1/L2-bypassing, agent-visible) 16B load. Result NOT valid until
// wait_vm0(). vmcnt is per-wave and completes in-order, so a manual vmcnt(0)
// is always safe alongside compiler-tracked vmem ops.
__device__ __forceinline__ void coh_load4(float4& d, const float* p) {
    asm volatile("global_load_dwordx4 %0, %1, off sc0 sc1" : "=v"(d) : "v"(p) : "memory");
}
__device__ __forceinline__ void coh_load4i(int4& d, const int* p) {
    asm volatile("global_load_dwordx4 %0, %1, off sc0 sc1" : "=v"(d) : "v"(p) : "memory");
}
__device__ __forceinline__ void wait_vm0() { asm volatile("s_waitcnt vmcnt(0)" ::: "memory"); }

// ---------------------------------------------------------------------------
// Pack w_hh (2048x512) -> wp[256 slices][512 k][12] (cols c=g*2+uu, pad 8..11)
// slice s owns h-units {2s, 2s+1}; col c<8: g=c>>1, uu=c&1 -> row g*512+2s+uu
// ---------------------------------------------------------------------------
__global__ __launch_bounds__(256) void pack_whh_v3(const float* __restrict__ whh,
                                                   float* __restrict__ wp)
{
    const int s = blockIdx.x;
    for (int idx = threadIdx.x; idx < 512 * 12; idx += 256) {
        const int k = idx / 12, c = idx % 12;
        float v = 0.f;
        if (c < 8) {
            const int g = c >> 1, uu = c & 1;
            v = whh[(size_t)(g * 512 + 2 * s + uu) * HH + k];
        }
        wp[(size_t)s * 6144 + idx] = v;
    }
}

__global__ __launch_bounds__(512) void init_flags(int* __restrict__ f)
{
    f[blockIdx.x * 512 + threadIdx.x] = 0;   // 256*512 = 2*SL*NBLK ints
}

// ---------------------------------------------------------------------------
// xg = X(16384x1024) @ W^T(1024x2048) + b1 + b2   (fp32, 128x128x16 tiles)
// ---------------------------------------------------------------------------
__global__ __launch_bounds__(256) void gemm_xg(
    const float* __restrict__ A,    // [16384][1024]
    const float* __restrict__ W,    // [2048][1024]
    const float* __restrict__ b1,
    const float* __restrict__ b2,
    float* __restrict__ C)          // [16384][2048]
{
    __shared__ float As[16][128];
    __shared__ float Bs[16][128];
    const int tid = threadIdx.x;
    const int m0 = blockIdx.x * 128;
    const int n0 = blockIdx.y * 128;
    const int tm = tid >> 4;
    const int tn = tid & 15;
    const int lr = tid >> 2;
    const int lc = (tid & 3) * 4;

    float acc[8][8];
    #pragma unroll
    for (int i = 0; i < 8; i++)
        #pragma unroll
        for (int j = 0; j < 8; j++) acc[i][j] = 0.f;

    for (int kt = 0; kt < DI; kt += 16) {
        #pragma unroll
        for (int p = 0; p < 2; p++) {
            float4 v = *(const float4*)(A + (size_t)(m0 + p * 64 + lr) * DI + kt + lc);
            As[lc + 0][p * 64 + lr] = v.x;
            As[lc + 1][p * 64 + lr] = v.y;
            As[lc + 2][p * 64 + lr] = v.z;
            As[lc + 3][p * 64 + lr] = v.w;
            float4 w = *(const float4*)(W + (size_t)(n0 + p * 64 + lr) * DI + kt + lc);
            Bs[lc + 0][p * 64 + lr] = w.x;
            Bs[lc + 1][p * 64 + lr] = w.y;
            Bs[lc + 2][p * 64 + lr] = w.z;
            Bs[lc + 3][p * 64 + lr] = w.w;
        }
        __syncthreads();
        #pragma unroll
        for (int kk = 0; kk < 16; kk++) {
            float4 a0 = *(const float4*)&As[kk][tm * 8];
            float4 a1 = *(const float4*)&As[kk][tm * 8 + 4];
            float4 bv0 = *(const float4*)&Bs[kk][tn * 8];
            float4 bv1 = *(const float4*)&Bs[kk][tn * 8 + 4];
            float a[8] = {a0.x, a0.y, a0.z, a0.w, a1.x, a1.y, a1.z, a1.w};
            float b[8] = {bv0.x, bv0.y, bv0.z, bv0.w, bv1.x, bv1.y, bv1.z, bv1.w};
            #pragma unroll
            for (int i = 0; i < 8; i++)
                #pragma unroll
                for (int j = 0; j < 8; j++)
                    acc[i][j] = fmaf(a[i], b[j], acc[i][j]);
        }
        __syncthreads();
    }
    #pragma unroll
    for (int i = 0; i < 8; i++) {
        const int m = m0 + tm * 8 + i;
        float* Crow = C + (size_t)m * G4 + n0 + tn * 8;
        #pragma unroll
        for (int j = 0; j < 8; j++) {
            const int n = n0 + tn * 8 + j;
            Crow[j] = acc[i][j] + b1[n] + b2[n];
        }
    }
}

// ---------------------------------------------------------------------------
// Flag-pipelined LSTM. Grid 512 (merged: dirs 0+1 concurrently, 2 blocks/CU)
// or grid 256 (single dir via dir_base). Block s owns h-units {2s,2s+1}
// (8 gate cols). Weights LDS-resident. Per step: poll prev-step flags (one
// wave, int4 coherent loads), stage H(t-1) in 4 chunks of 16B coherent loads
// (next chunk prefetched during compute), GEMM, shfl k-reduce, skewed LDS
// cross-wave reduce, gate nonlinearity (c in regs), publish h (agent atomic
// stores), release flag.
// ---------------------------------------------------------------------------
__global__ __launch_bounds__(512, 4) void lstm_flag(
    const float* __restrict__ xg_f, const float* __restrict__ xg_b,
    const float* __restrict__ wp_f, const float* __restrict__ wp_b,
    float* __restrict__ Hf, float* __restrict__ Hb,
    int* __restrict__ flag_f, int* __restrict__ flag_b,
    float* __restrict__ out, int dir_base)
{
    __shared__ float w_s[512 * 12];              // 24576 B, persistent
    __shared__ float hs[128 * 68];               // 34816 B, reused per chunk
    float* const part = hs;                      // [8][572] overlay
    float* const g_s  = hs + 8 * 572;            // [8][65]  overlay

    const int dir = dir_base + (blockIdx.x >> 8);
    const int s   = blockIdx.x & 255;
    const float* xg  = dir ? xg_b : xg_f;
    const float* wp  = dir ? wp_b : wp_f;
    float* Hbuf      = dir ? Hb : Hf;
    int*   flag      = dir ? flag_b : flag_f;
    const int reverse = dir;
    const int col_off = dir * HH;

    const int tid = threadIdx.x;
    const int ks  = tid >> 4;        // 0..31 k-slice
    const int bt  = (tid >> 1) & 7;  // 0..7 batch tile
    const int ct  = tid & 1;         // 0..1 col tile (4 cols each)
    const int wv  = tid >> 6;        // wave 0..7
    const int bb  = tid >> 3;        // gate-batch 0..63
    const int cc  = tid & 7;         // gate-col 0..7

    // stage weights once (1536 float4)
    {
        const float4* src = (const float4*)(wp + (size_t)s * 6144);
        float4* dst = (float4*)w_s;
        for (int i = tid; i < 1536; i += 512) dst[i] = src[i];
    }

    float cst = 0.f;                  // c-state: tid<128 owns (b=tid&63, uu=tid>>6)
    float4 r[4];
    float4 acc[8];

    for (int step = 0; step < SL; ++step) {
        const int t = reverse ? (SL - 1 - step) : step;
        // early xg load: latency hidden behind poll + staging
        const float myxg = xg[(size_t)(t * BS + bb) * G4 + (cc >> 1) * 512 + 2 * s + (cc & 1)];

        if (step > 0) {
            if (tid < 64) {
                const int* fp = flag + (step - 1) * NBLK + tid * 4;
                int4 f;
                for (;;) {
                    coh_load4i(f, fp);
                    wait_vm0();
                    if (f.x & f.y & f.z & f.w) break;
                    __builtin_amdgcn_s_sleep(1);
                }
            }
            __syncthreads();   // flags seen; also protects w_s/hs reuse

            const float* hsrc = Hbuf + ((step + 1) & 1) * (512 * 64);
            // prefetch chunk 0: 4 x float4 per thread (32 KB/chunk)
            #pragma unroll
            for (int i = 0; i < 4; ++i)
                coh_load4(r[i], hsrc + (size_t)(i * 512 + tid) * 4);

            #pragma unroll
            for (int i = 0; i < 8; ++i) acc[i] = make_float4(0.f, 0.f, 0.f, 0.f);

            for (int kc = 0; kc < 4; ++kc) {
                if (kc) __syncthreads();           // prev chunk consumed
                wait_vm0();
                #pragma unroll
                for (int i = 0; i < 4; ++i) {
                    const int idx = i * 512 + tid;        // float4 index in chunk
                    const int k = idx >> 4, b4 = (idx & 15) * 4;
                    *(float4*)&hs[k * 68 + b4] = r[i];
                }
                __syncthreads();                   // hs ready
                if (kc < 3) {                      // prefetch next chunk during compute
                    const float* base = hsrc + (size_t)(kc + 1) * 8192;
                    #pragma unroll
                    for (int i = 0; i < 4; ++i)
                        coh_load4(r[i], base + (size_t)(i * 512 + tid) * 4);
                }
                #pragma unroll
                for (int j = 0; j < 4; ++j) {
                    const int kk = ks + 32 * j;
                    const int kg = kc * 128 + kk;
                    const float4 w = *(const float4*)&w_s[kg * 12 + ct * 4];
                    const float* hp = &hs[kk * 68 + 8 * bt];
                    const float2 h01 = *(const float2*)(hp + 0);
                    const float2 h23 = *(const float2*)(hp + 2);
                    const float2 h45 = *(const float2*)(hp + 4);
                    const float2 h67 = *(const float2*)(hp + 6);
                    const float hv[8] = {h01.x, h01.y, h23.x, h23.y, h45.x, h45.y, h67.x, h67.y};
                    #pragma unroll
                    for (int i = 0; i < 8; ++i) {
                        acc[i].x = fmaf(hv[i], w.x, acc[i].x);
                        acc[i].y = fmaf(hv[i], w.y, acc[i].y);
                        acc[i].z = fmaf(hv[i], w.z, acc[i].z);
                        acc[i].w = fmaf(hv[i], w.w, acc[i].w);
                    }
                }
            }
            // k-reduce within wave (ks bits 4,5 of lane)
            #pragma unroll
            for (int i = 0; i < 8; ++i) {
                acc[i].x += __shfl_xor(acc[i].x, 16);
                acc[i].y += __shfl_xor(acc[i].y, 16);
                acc[i].z += __shfl_xor(acc[i].z, 16);
                acc[i].w += __shfl_xor(acc[i].w, 16);
                acc[i].x += __shfl_xor(acc[i].x, 32);
                acc[i].y += __shfl_xor(acc[i].y, 32);
                acc[i].z += __shfl_xor(acc[i].z, 32);
                acc[i].w += __shfl_xor(acc[i].w, 32);
            }
            __syncthreads();                       // hs reads done; part overlays hs
            if ((tid & 63) < 16) {                 // skew bt*8 -> 2-way banks (free)
                #pragma unroll
                for (int i = 0; i < 8; ++i)
                    *(float4*)&part[wv * 572 + (8 * bt + i) * 8 + ct * 4 + bt * 8] = acc[i];
            }
            __syncthreads();
        }

        // cross-wave reduce + xg: gate idx = tid (64 b x 8 c)
        {
            float v = myxg;
            if (step > 0) {
                const int skew = 8 * (tid >> 6);
                #pragma unroll
                for (int w = 0; w < 8; ++w) v += part[w * 572 + tid + skew];
            }
            g_s[cc * 65 + bb] = v;
        }
        __syncthreads();

        if (tid < 128) {
            const int b = tid & 63, uu = tid >> 6;
            const float ig = sigm(g_s[(0 + uu) * 65 + b]);
            const float fg = sigm(g_s[(2 + uu) * 65 + b]);
            const float gg = tanhf(g_s[(4 + uu) * 65 + b]);
            const float og = sigm(g_s[(6 + uu) * 65 + b]);
            cst = fg * cst + ig * gg;
            const float h = og * tanhf(cst);
            __hip_atomic_store(Hbuf + (step & 1) * (512 * 64) + (2 * s + uu) * 64 + b, h,
                               __ATOMIC_RELAXED, __HIP_MEMORY_SCOPE_AGENT);
            out[(size_t)(t * BS + b) * C2 + col_off + 2 * s + uu] = h;
        }
        __syncthreads();   // each wave drains vmcnt before barrier => h visible
        if (tid == 0)
            __hip_atomic_store(flag + step * NBLK + s, 1,
                               __ATOMIC_RELEASE, __HIP_MEMORY_SCOPE_AGENT);
    }
}

// ---------------------------------------------------------------------------
// BatchNorm stats: one block per channel (two-pass mean/var)
// ---------------------------------------------------------------------------
__global__ __launch_bounds__(256) void bn_stats(
    const float* __restrict__ X, float* __restrict__ mean, float* __restrict__ istd)
{
    const int ch = blockIdx.x, tid = threadIdx.x;
    __shared__ float red[256];
    float s = 0.f;
    for (int r = tid; r < NR; r += 256) s += X[(size_t)r * C2 + ch];
    red[tid] = s; __syncthreads();
    for (int o = 128; o; o >>= 1) { if (tid < o) red[tid] += red[tid + o]; __syncthreads(); }
    const float mu = red[0] * (1.f / NR);
    __syncthreads();
    float v = 0.f;
    for (int r = tid; r < NR; r += 256) { const float d = X[(size_t)r * C2 + ch] - mu; v = fmaf(d, d, v); }
    red[tid] = v; __syncthreads();
    for (int o = 128; o; o >>= 1) { if (tid < o) red[tid] += red[tid + o]; __syncthreads(); }
    if (tid == 0) { mean[ch] = mu; istd[ch] = rsqrtf(red[0] * (1.f / NR) + 1e-5f); }
}

// ---------------------------------------------------------------------------
// Fold BN into linear
// ---------------------------------------------------------------------------
__global__ void fold_lin(const float* __restrict__ lin_w, const float* __restrict__ lin_b,
                         const float* __restrict__ gamma, const float* __restrict__ beta,
                         const float* __restrict__ mean, const float* __restrict__ istd,
                         float* __restrict__ Wf, float* __restrict__ ct)
{
    const int t = blockIdx.x, tid = threadIdx.x;
    __shared__ float red[256];
    float acc = 0.f;
    for (int cc = tid; cc < C2; cc += 256) {
        const float w = lin_w[t * C2 + cc];
        const float g = gamma[cc] * istd[cc];
        Wf[t * C2 + cc] = w * g;
        acc = fmaf(beta[cc] - mean[cc] * g, w, acc);
    }
    red[tid] = acc; __syncthreads();
    for (int o = 128; o; o >>= 1) { if (tid < o) red[tid] += red[tid + o]; __syncthreads(); }
    if (tid == 0) ct[t] = red[0] + lin_b[t];
}

// ---------------------------------------------------------------------------
// Emission logits E[b][s][t]  (wave per row)
// ---------------------------------------------------------------------------
__global__ __launch_bounds__(256) void emit_logits(
    const float* __restrict__ X, const float* __restrict__ Wf,
    const float* __restrict__ ct, float* __restrict__ E)
{
    const int r = blockIdx.x * 4 + (threadIdx.x >> 6);
    const int lane = threadIdx.x & 63;
    const float* xr = X + (size_t)r * C2;
    float acc[TT];
    #pragma unroll
    for (int t = 0; t < TT; t++) acc[t] = 0.f;
    for (int i = 0; i < C2 / 64; i++) {
        const int cc = i * 64 + lane;
        const float xv = xr[cc];
        #pragma unroll
        for (int t = 0; t < TT; t++) acc[t] = fmaf(xv, Wf[t * C2 + cc], acc[t]);
    }
    #pragma unroll
    for (int t = 0; t < TT; t++)
        for (int off = 32; off; off >>= 1) acc[t] += __shfl_xor(acc[t], off);
    if (lane == 0) {
        const int b = r & (BS - 1), s = r >> 6;
        float* Er = E + ((size_t)b * SL + s) * TT;
        #pragma unroll
        for (int t = 0; t < TT; t++) Er[t] = acc[t] + ct[t];
    }
}

// ---------------------------------------------------------------------------
// CRF log-likelihood per batch element
// ---------------------------------------------------------------------------
__global__ __launch_bounds__(64) void crf_llh(
    const float* __restrict__ E, const int* __restrict__ mask,
    const int* __restrict__ labels, const float* __restrict__ startv,
    const float* __restrict__ endv, const float* __restrict__ trans,
    float* __restrict__ res)
{
    const int b = blockIdx.x, lane = threadIdx.x;
    __shared__ float tr[TT][TT];
    for (int i = lane; i < TT * TT; i += 64) tr[i / TT][i % TT] = trans[i];
    __syncthreads();
    const float* Eb = E + (size_t)b * SL * TT;
    const int j = (lane < TT) ? lane : 0;

    float alpha = -1e30f;
    if (lane < TT) alpha = startv[lane] + Eb[lane];

    float numacc = 0.f; int len = 0;
    for (int t = lane; t < SL; t += 64) {
        const int mt = mask[t * BS + b];
        len += (mt != 0);
        if (t >= 1 && mt) {
            const int yp = labels[(t - 1) * BS + b];
            const int yt = labels[t * BS + b];
            numacc += tr[yp][yt] + Eb[t * TT + yt];
        }
    }
    for (int off = 32; off; off >>= 1) {
        numacc += __shfl_xor(numacc, off);
        len += __shfl_xor(len, off);
    }

    for (int t = 1; t < SL; ++t) {
        const int mt = mask[t * BS + b];
        if (mt) {
            float av[TT];
            #pragma unroll
            for (int i = 0; i < TT; i++) av[i] = __shfl(alpha, i);
            const float e = (lane < TT) ? Eb[t * TT + lane] : 0.f;
            float mx = -1e30f;
            #pragma unroll
            for (int i = 0; i < TT; i++) mx = fmaxf(mx, av[i] + tr[i][j]);
            float s = 0.f;
            #pragma unroll
            for (int i = 0; i < TT; i++) s += expf(av[i] + tr[i][j] - mx);
            const float nxt = mx + logf(s) + e;
            if (lane < TT) alpha = nxt;
        }
    }
    float v = (lane < TT) ? alpha + endv[lane] : -1e30f;
    float mx = v;
    for (int off = 32; off; off >>= 1) mx = fmaxf(mx, __shfl_xor(mx, off));
    float se = (lane < TT) ? expf(v - mx) : 0.f;
    for (int off = 32; off; off >>= 1) se += __shfl_xor(se, off);
    const float Z = mx + logf(se);

    if (lane == 0) {
        const int y0 = labels[b];
        float num = startv[y0] + Eb[y0] + numacc;
        const int last = len - 1;
        const int yl = labels[last * BS + b];
        num += endv[yl];
        res[b] = num - Z;
    }
}

__global__ __launch_bounds__(64) void loss_reduce(const float* __restrict__ res, float* __restrict__ out)
{
    const int lane = threadIdx.x;
    float v = res[lane];
    for (int off = 32; off; off >>= 1) v += __shfl_xor(v, off);
    if (lane == 0) out[0] = -v;
}

// ---------------------------------------------------------------------------
// Viterbi per batch element
// ---------------------------------------------------------------------------
__global__ __launch_bounds__(64) void viterbi(
    const float* __restrict__ E, const int* __restrict__ mask,
    const float* __restrict__ startv, const float* __restrict__ endv,
    const float* __restrict__ trans, float* __restrict__ preds)
{
    const int b = blockIdx.x, lane = threadIdx.x;
    __shared__ float tr[TT][TT];
    __shared__ unsigned char bp[SL][TT];
    for (int i = lane; i < TT * TT; i += 64) tr[i / TT][i % TT] = trans[i];
    __syncthreads();
    const float* Eb = E + (size_t)b * SL * TT;
    const int j = (lane < TT) ? lane : 0;

    float score = (lane < TT) ? startv[lane] + Eb[lane] : -1e30f;
    for (int t = 1; t < SL; ++t) {
        float av[TT];
        #pragma unroll
        for (int i = 0; i < TT; i++) av[i] = __shfl(score, i);
        float best = -1e30f; int bi = 0;
        #pragma unroll
        for (int i = 0; i < TT; i++) {
            const float cand = av[i] + tr[i][j];
            if (cand > best) { best = cand; bi = i; }
        }
        const int mt = mask[t * BS + b];
        if (lane < TT) {
            bp[t][lane] = (unsigned char)bi;
            if (mt) score = best + Eb[t * TT + lane];
        }
    }
    float v = (lane < TT) ? score + endv[lane] : -1e30f;
    float mx = v;
    for (int off = 32; off; off >>= 1) mx = fmaxf(mx, __shfl_xor(mx, off));
    unsigned long long ball = __ballot(v == mx);
    const int last_tag = __ffsll(ball) - 1;
    __syncthreads();

    if (lane == 0) {
        int tag = last_tag;
        float* pb = preds + (size_t)b * SL;
        for (int t = SL - 1; t >= 1; --t) {
            const int mt = mask[t * BS + b];
            pb[t] = mt ? (float)tag : 0.f;
            if (mt) tag = bp[t][tag];
        }
        pb[0] = mask[b] ? (float)tag : 0.f;
    }
}

// ---------------------------------------------------------------------------
extern "C" void kernel_launch(void* const* d_in, const int* in_sizes, int n_in,
                              void* d_out, int out_size, void* d_ws, size_t ws_size,
                              hipStream_t stream)
{
    const float* word    = (const float*)d_in[0];
    const int*   mask    = (const int*)  d_in[1];
    const int*   labels  = (const int*)  d_in[2];
    const float* w_ih_f  = (const float*)d_in[3];
    const float* w_hh_f  = (const float*)d_in[4];
    const float* b_ih_f  = (const float*)d_in[5];
    const float* b_hh_f  = (const float*)d_in[6];
    const float* w_ih_b  = (const float*)d_in[7];
    const float* w_hh_b  = (const float*)d_in[8];
    const float* b_ih_b  = (const float*)d_in[9];
    const float* b_hh_b  = (const float*)d_in[10];
    const float* gamma   = (const float*)d_in[11];
    const float* beta    = (const float*)d_in[12];
    const float* lin_w   = (const float*)d_in[13];
    const float* lin_b   = (const float*)d_in[14];
    const float* c_start = (const float*)d_in[15];
    const float* c_end   = (const float*)d_in[16];
    const float* c_trans = (const float*)d_in[17];
    float* out = (float*)d_out;
    (void)in_sizes; (void)n_in; (void)out_size;

    char* ws = (char*)d_ws;
    size_t off = 0;
    auto alloc = [&](size_t bytes) {
        void* p = ws + off;
        off += (bytes + 255) & ~(size_t)255;
        return p;
    };
    float* XG_F  = (float*)alloc((size_t)NR * G4 * 4);          // 128 MB
    float* WPK_F = (float*)alloc((size_t)256 * 6144 * 4);       // 6.3 MB
    float* WPK_B = (float*)alloc((size_t)256 * 6144 * 4);       // 6.3 MB
    float* LOUT  = (float*)alloc((size_t)NR * C2 * 4);          // 64 MB
    float* HB_F  = (float*)alloc((size_t)2 * 512 * 64 * 4);     // 256 KB
    float* HB_B  = (float*)alloc((size_t)2 * 512 * 64 * 4);     // 256 KB
    int*   FLAGS = (int*)  alloc((size_t)2 * SL * NBLK * 4);    // 512 KB
    float* MEAN  = (float*)alloc(C2 * 4);
    float* ISTD  = (float*)alloc(C2 * 4);
    float* WF    = (float*)alloc(TT * C2 * 4);
    float* CT    = (float*)alloc(TT * 4);
    float* Ebuf  = (float*)alloc((size_t)BS * SL * TT * 4);
    float* RES   = (float*)alloc(BS * 4);
    float* XG_B  = (float*)alloc((size_t)NR * G4 * 4);          // 128 MB (merged only)
    const bool merged = (ws_size >= off);                       // ~336 MB needed
    if (!merged) XG_B = XG_F;                                   // sequential reuse

    init_flags<<<256, 512, 0, stream>>>(FLAGS);
    pack_whh_v3<<<256, 256, 0, stream>>>(w_hh_f, WPK_F);
    pack_whh_v3<<<256, 256, 0, stream>>>(w_hh_b, WPK_B);

    if (merged) {
        gemm_xg<<<dim3(NR / 128, G4 / 128), 256, 0, stream>>>(word, w_ih_f, b_ih_f, b_hh_f, XG_F);
        gemm_xg<<<dim3(NR / 128, G4 / 128), 256, 0, stream>>>(word, w_ih_b, b_ih_b, b_hh_b, XG_B);
        // both directions concurrently: 512 blocks, 2/CU (launch_bounds caps VGPR)
        lstm_flag<<<2 * NBLK, 512, 0, stream>>>(XG_F, XG_B, WPK_F, WPK_B, HB_F, HB_B,
                                                FLAGS, FLAGS + SL * NBLK, LOUT, 0);
    } else {
        gemm_xg<<<dim3(NR / 128, G4 / 128), 256, 0, stream>>>(word, w_ih_f, b_ih_f, b_hh_f, XG_F);
        lstm_flag<<<NBLK, 512, 0, stream>>>(XG_F, XG_B, WPK_F, WPK_B, HB_F, HB_B,
                                            FLAGS, FLAGS + SL * NBLK, LOUT, 0);
        gemm_xg<<<dim3(NR / 128, G4 / 128), 256, 0, stream>>>(word, w_ih_b, b_ih_b, b_hh_b, XG_F);
        lstm_flag<<<NBLK, 512, 0, stream>>>(XG_F, XG_B, WPK_F, WPK_B, HB_F, HB_B,
                                            FLAGS, FLAGS + SL * NBLK, LOUT, 1);
    }

    bn_stats<<<C2, 256, 0, stream>>>(LOUT, MEAN, ISTD);
    fold_lin<<<TT, 256, 0, stream>>>(lin_w, lin_b, gamma, beta, MEAN, ISTD, WF, CT);
    emit_logits<<<NR / 4, 256, 0, stream>>>(LOUT, WF, CT, Ebuf);

    crf_llh<<<BS, 64, 0, stream>>>(Ebuf, mask, labels, c_start, c_end, c_trans, RES);
    loss_reduce<<<1, 64, 0, stream>>>(RES, out);
    viterbi<<<BS, 64, 0, stream>>>(Ebuf, mask, c_start, c_end, c_trans, out + 1);
}

// Round 6
// 9408.311 us; speedup vs baseline: 3.8549x; 1.1682x over previous
//
#include <hip/hip_runtime.h>
#include <hip/hip_bf16.h>
#include <math.h>

// Problem constants
#define SL 256
#define BS 64
#define DI 1024
#define HH 512
#define TT 17
#define NR (SL*BS)        // 16384 rows
#define G4 (4*HH)         // 2048 gates
#define C2 (2*HH)         // 1024 channels
#define NBLK 256          // blocks per direction in lstm_flag

__device__ __forceinline__ float sigm(float x) { return 1.f / (1.f + expf(-x)); }

typedef float vfloat4 __attribute__((ext_vector_type(4)));

// Coherent (L1/L2-bypassing, agent-visible) 16B accesses. Loads not valid
// until wait_vm0(); stores complete (visible at coherent point) after
// wait_vm0(). vmcnt is per-wave, in-order — manual waits are safe.
__device__ __forceinline__ void coh_load4(float4& d, const float* p) {
    asm volatile("global_load_dwordx4 %0, %1, off sc0 sc1" : "=v"(d) : "v"(p) : "memory");
}
__device__ __forceinline__ void coh_load4i(int4& d, const int* p) {
    asm volatile("global_load_dwordx4 %0, %1, off sc0 sc1" : "=v"(d) : "v"(p) : "memory");
}
__device__ __forceinline__ void coh_store4(const float4& d, float* p) {
    vfloat4 t; t.x = d.x; t.y = d.y; t.z = d.z; t.w = d.w;   // ext-vector = direct VGPR quad
    asm volatile("global_store_dwordx4 %0, %1, off sc0 sc1" :: "v"(p), "v"(t) : "memory");
}
__device__ __forceinline__ void wait_vm0() { asm volatile("s_waitcnt vmcnt(0)" ::: "memory"); }

// ---------------------------------------------------------------------------
// Pack w_hh (2048x512) -> wp[256 slices][512 k][12] (cols c=g*2+uu, pad 8..11)
// slice s owns h-units {2s, 2s+1}; col c<8: g=c>>1, uu=c&1 -> row g*512+2s+uu
// ---------------------------------------------------------------------------
__global__ __launch_bounds__(256) void pack_whh_v3(const float* __restrict__ whh,
                                                   float* __restrict__ wp)
{
    const int s = blockIdx.x;
    for (int idx = threadIdx.x; idx < 512 * 12; idx += 256) {
        const int k = idx / 12, c = idx % 12;
        float v = 0.f;
        if (c < 8) {
            const int g = c >> 1, uu = c & 1;
            v = whh[(size_t)(g * 512 + 2 * s + uu) * HH + k];
        }
        wp[(size_t)s * 6144 + idx] = v;
    }
}

__global__ __launch_bounds__(512) void init_flags(int* __restrict__ f)
{
    f[blockIdx.x * 512 + threadIdx.x] = 0;   // 256*512 = 2*SL*NBLK ints
}

// ---------------------------------------------------------------------------
// xg GEMM: X(16384x1024) @ W^T(1024x2048) + b1 + b2, written SLICE-MAJOR:
// XG2[((s*SL + t)*BS + b)*8 + c], s = (n&511)>>1, c = (n>>9)*2 + (n&1).
// Each LSTM block then reads 2 KB contiguous per step.
// ---------------------------------------------------------------------------
__global__ __launch_bounds__(256) void gemm_xg(
    const float* __restrict__ A,    // [16384][1024]
    const float* __restrict__ W,    // [2048][1024]
    const float* __restrict__ b1,
    const float* __restrict__ b2,
    float* __restrict__ C)          // slice-major xg
{
    __shared__ float As[16][128];
    __shared__ float Bs[16][128];
    const int tid = threadIdx.x;
    const int m0 = blockIdx.x * 128;
    const int n0 = blockIdx.y * 128;
    const int tm = tid >> 4;
    const int tn = tid & 15;
    const int lr = tid >> 2;
    const int lc = (tid & 3) * 4;

    float acc[8][8];
    #pragma unroll
    for (int i = 0; i < 8; i++)
        #pragma unroll
        for (int j = 0; j < 8; j++) acc[i][j] = 0.f;

    for (int kt = 0; kt < DI; kt += 16) {
        #pragma unroll
        for (int p = 0; p < 2; p++) {
            float4 v = *(const float4*)(A + (size_t)(m0 + p * 64 + lr) * DI + kt + lc);
            As[lc + 0][p * 64 + lr] = v.x;
            As[lc + 1][p * 64 + lr] = v.y;
            As[lc + 2][p * 64 + lr] = v.z;
            As[lc + 3][p * 64 + lr] = v.w;
            float4 w = *(const float4*)(W + (size_t)(n0 + p * 64 + lr) * DI + kt + lc);
            Bs[lc + 0][p * 64 + lr] = w.x;
            Bs[lc + 1][p * 64 + lr] = w.y;
            Bs[lc + 2][p * 64 + lr] = w.z;
            Bs[lc + 3][p * 64 + lr] = w.w;
        }
        __syncthreads();
        #pragma unroll
        for (int kk = 0; kk < 16; kk++) {
            float4 a0 = *(const float4*)&As[kk][tm * 8];
            float4 a1 = *(const float4*)&As[kk][tm * 8 + 4];
            float4 bv0 = *(const float4*)&Bs[kk][tn * 8];
            float4 bv1 = *(const float4*)&Bs[kk][tn * 8 + 4];
            float a[8] = {a0.x, a0.y, a0.z, a0.w, a1.x, a1.y, a1.z, a1.w};
            float b[8] = {bv0.x, bv0.y, bv0.z, bv0.w, bv1.x, bv1.y, bv1.z, bv1.w};
            #pragma unroll
            for (int i = 0; i < 8; i++)
                #pragma unroll
                for (int j = 0; j < 8; j++)
                    acc[i][j] = fmaf(a[i], b[j], acc[i][j]);
        }
        __syncthreads();
    }
    // epilogue: slice-major scatter (float2 per slice)
    const int g  = n0 >> 9;                    // gate, constant per n-tile
    const int u0 = (n0 & 511) + tn * 8;        // first unit (even)
    const int s0 = u0 >> 1;                    // first slice
    #pragma unroll
    for (int i = 0; i < 8; i++) {
        const int m = m0 + tm * 8 + i;
        const int mt = m >> 6, mb = m & 63;
        #pragma unroll
        for (int sj = 0; sj < 4; sj++) {
            const int n = n0 + tn * 8 + sj * 2;
            float2 v;
            v.x = acc[i][sj * 2 + 0] + b1[n + 0] + b2[n + 0];
            v.y = acc[i][sj * 2 + 1] + b1[n + 1] + b2[n + 1];
            *(float2*)(C + ((((size_t)(s0 + sj) * SL + mt) * BS + mb) << 3) + g * 2) = v;
        }
    }
}

// ---------------------------------------------------------------------------
// Flag-pipelined LSTM. Grid 512 (merged dirs, 2 blocks/CU) or 256 (one dir).
// Block s owns h-units {2s,2s+1} (8 gate cols). Weights LDS-resident.
// Per step: poll prev flags (1 wave, int4 coherent), stage H(t-1) in 4 chunks
// of coherent dwordx4 (next chunk prefetched during compute), GEMM, shfl
// k-reduce, skewed LDS cross-wave reduce, gate nonlinearity (c in regs),
// publish h via LDS-repacked coherent dwordx4 (coalesced!), release flag.
// ---------------------------------------------------------------------------
__global__ __launch_bounds__(512, 4) void lstm_flag(
    const float* __restrict__ xg_f, const float* __restrict__ xg_b,  // slice-major
    const float* __restrict__ wp_f, const float* __restrict__ wp_b,
    float* __restrict__ Hf, float* __restrict__ Hb,
    int* __restrict__ flag_f, int* __restrict__ flag_b,
    float* __restrict__ out,          // channel-major [C2][NR]
    int dir_base)
{
    __shared__ float w_s[512 * 12];              // 24576 B, persistent
    __shared__ float hs[128 * 68];               // 34816 B, reused per chunk
    __shared__ float hpub[128];                  //   512 B
    float* const part = hs;                      // [8][572] overlay
    float* const g_s  = hs + 8 * 572;            // [8][65]  overlay

    const int dir = dir_base + (blockIdx.x >> 8);
    const int s   = blockIdx.x & 255;
    const float* xg  = dir ? xg_b : xg_f;
    const float* wp  = dir ? wp_b : wp_f;
    float* Hbuf      = dir ? Hb : Hf;
    int*   flag      = dir ? flag_b : flag_f;
    const int reverse = dir;
    const int col_off = dir * HH;

    const int tid = threadIdx.x;
    const int ks  = tid >> 4;        // 0..31 k-slice
    const int bt  = (tid >> 1) & 7;  // 0..7 batch tile
    const int ct  = tid & 1;         // 0..1 col tile (4 cols each)
    const int wv  = tid >> 6;        // wave 0..7
    const int bb  = tid >> 3;        // gate-batch 0..63
    const int cc  = tid & 7;         // gate-col 0..7

    // stage weights once (1536 float4)
    {
        const float4* src = (const float4*)(wp + (size_t)s * 6144);
        float4* dst = (float4*)w_s;
        for (int i = tid; i < 1536; i += 512) dst[i] = src[i];
    }

    const float* xgs = xg + (size_t)s * (SL * 512);
    float cst = 0.f;                  // c-state: tid<128 owns (b=tid&63, uu=tid>>6)
    float4 r[4];
    float4 acc[8];

    for (int step = 0; step < SL; ++step) {
        const int t = reverse ? (SL - 1 - step) : step;
        // coalesced xg load (1 dword/thread, 2 KB/block/step)
        const float myxg = xgs[t * 512 + tid];

        if (step > 0) {
            if (tid < 64) {
                const int* fp = flag + (step - 1) * NBLK + tid * 4;
                int4 f;
                for (;;) {
                    coh_load4i(f, fp);
                    wait_vm0();
                    if (f.x & f.y & f.z & f.w) break;
                    __builtin_amdgcn_s_sleep(1);
                }
            }
            __syncthreads();   // flags seen; also protects w_s/hs reuse

            const float* hsrc = Hbuf + ((step + 1) & 1) * (512 * 64);
            // prefetch chunk 0: 4 x float4 per thread (32 KB/chunk)
            #pragma unroll
            for (int i = 0; i < 4; ++i)
                coh_load4(r[i], hsrc + (size_t)(i * 512 + tid) * 4);

            #pragma unroll
            for (int i = 0; i < 8; ++i) acc[i] = make_float4(0.f, 0.f, 0.f, 0.f);

            for (int kc = 0; kc < 4; ++kc) {
                if (kc) __syncthreads();           // prev chunk consumed
                wait_vm0();
                #pragma unroll
                for (int i = 0; i < 4; ++i) {
                    const int idx = i * 512 + tid;        // float4 index in chunk
                    const int k = idx >> 4, b4 = (idx & 15) * 4;
                    *(float4*)&hs[k * 68 + b4] = r[i];
                }
                __syncthreads();                   // hs ready
                if (kc < 3) {                      // prefetch next chunk during compute
                    const float* base = hsrc + (size_t)(kc + 1) * 8192;
                    #pragma unroll
                    for (int i = 0; i < 4; ++i)
                        coh_load4(r[i], base + (size_t)(i * 512 + tid) * 4);
                }
                #pragma unroll
                for (int j = 0; j < 4; ++j) {
                    const int kk = ks + 32 * j;
                    const int kg = kc * 128 + kk;
                    const float4 w = *(const float4*)&w_s[kg * 12 + ct * 4];
                    const float* hp = &hs[kk * 68 + 8 * bt];
                    const float2 h01 = *(const float2*)(hp + 0);
                    const float2 h23 = *(const float2*)(hp + 2);
                    const float2 h45 = *(const float2*)(hp + 4);
                    const float2 h67 = *(const float2*)(hp + 6);
                    const float hv[8] = {h01.x, h01.y, h23.x, h23.y, h45.x, h45.y, h67.x, h67.y};
                    #pragma unroll
                    for (int i = 0; i < 8; ++i) {
                        acc[i].x = fmaf(hv[i], w.x, acc[i].x);
                        acc[i].y = fmaf(hv[i], w.y, acc[i].y);
                        acc[i].z = fmaf(hv[i], w.z, acc[i].z);
                        acc[i].w = fmaf(hv[i], w.w, acc[i].w);
                    }
                }
            }
            // k-reduce within wave (ks bits 4,5 of lane)
            #pragma unroll
            for (int i = 0; i < 8; ++i) {
                acc[i].x += __shfl_xor(acc[i].x, 16);
                acc[i].y += __shfl_xor(acc[i].y, 16);
                acc[i].z += __shfl_xor(acc[i].z, 16);
                acc[i].w += __shfl_xor(acc[i].w, 16);
                acc[i].x += __shfl_xor(acc[i].x, 32);
                acc[i].y += __shfl_xor(acc[i].y, 32);
                acc[i].z += __shfl_xor(acc[i].z, 32);
                acc[i].w += __shfl_xor(acc[i].w, 32);
            }
            __syncthreads();                       // hs reads done; part overlays hs
            if ((tid & 63) < 16) {                 // skew bt*8 -> 2-way banks (free)
                #pragma unroll
                for (int i = 0; i < 8; ++i)
                    *(float4*)&part[wv * 572 + (8 * bt + i) * 8 + ct * 4 + bt * 8] = acc[i];
            }
            __syncthreads();
        }

        // cross-wave reduce + xg: gate idx = tid (64 b x 8 c)
        {
            float v = myxg;
            if (step > 0) {
                const int skew = 8 * (tid >> 6);
                #pragma unroll
                for (int w = 0; w < 8; ++w) v += part[w * 572 + tid + skew];
            }
            g_s[cc * 65 + bb] = v;
        }
        __syncthreads();

        if (tid < 128) {
            const int b = tid & 63, uu = tid >> 6;
            const float ig = sigm(g_s[(0 + uu) * 65 + b]);
            const float fg = sigm(g_s[(2 + uu) * 65 + b]);
            const float gg = tanhf(g_s[(4 + uu) * 65 + b]);
            const float og = sigm(g_s[(6 + uu) * 65 + b]);
            cst = fg * cst + ig * gg;
            hpub[tid] = og * tanhf(cst);           // [uu][b]
        }
        __syncthreads();
        if (tid < 8) {                             // coalesced publication
            const float4 v = *(const float4*)&hpub[tid * 16];
            coh_store4(v, Hbuf + (step & 1) * (512 * 64) + 2 * s * 64 + tid * 16);
            *(float4*)(out + (size_t)(col_off + 2 * s + (tid >> 2)) * NR
                           + (size_t)t * 64 + (tid & 3) * 16) = v;
        }
        if (wv == 0) wait_vm0();                   // h at coherent point
        __syncthreads();
        if (tid == 0)
            __hip_atomic_store(flag + step * NBLK + s, 1,
                               __ATOMIC_RELEASE, __HIP_MEMORY_SCOPE_AGENT);
    }
}

// ---------------------------------------------------------------------------
// BatchNorm stats over channel-major X2 [C2][NR]: block per channel
// ---------------------------------------------------------------------------
__global__ __launch_bounds__(256) void bn_stats(
    const float* __restrict__ X2, float* __restrict__ mean, float* __restrict__ istd)
{
    const int ch = blockIdx.x, tid = threadIdx.x;
    const float* base = X2 + (size_t)ch * NR;
    __shared__ float red[256];
    float s = 0.f;
    for (int i = tid * 4; i < NR; i += 1024) {
        const float4 v = *(const float4*)(base + i);
        s += v.x + v.y + v.z + v.w;
    }
    red[tid] = s; __syncthreads();
    for (int o = 128; o; o >>= 1) { if (tid < o) red[tid] += red[tid + o]; __syncthreads(); }
    const float mu = red[0] * (1.f / NR);
    __syncthreads();
    float vv = 0.f;
    for (int i = tid * 4; i < NR; i += 1024) {
        const float4 v = *(const float4*)(base + i);
        const float d0 = v.x - mu, d1 = v.y - mu, d2 = v.z - mu, d3 = v.w - mu;
        vv += d0 * d0 + d1 * d1 + d2 * d2 + d3 * d3;
    }
    red[tid] = vv; __syncthreads();
    for (int o = 128; o; o >>= 1) { if (tid < o) red[tid] += red[tid + o]; __syncthreads(); }
    if (tid == 0) { mean[ch] = mu; istd[ch] = rsqrtf(red[0] * (1.f / NR) + 1e-5f); }
}

// ---------------------------------------------------------------------------
// Fold BN into linear
// ---------------------------------------------------------------------------
__global__ void fold_lin(const float* __restrict__ lin_w, const float* __restrict__ lin_b,
                         const float* __restrict__ gamma, const float* __restrict__ beta,
                         const float* __restrict__ mean, const float* __restrict__ istd,
                         float* __restrict__ Wf, float* __restrict__ ct)
{
    const int t = blockIdx.x, tid = threadIdx.x;
    __shared__ float red[256];
    float acc = 0.f;
    for (int cc = tid; cc < C2; cc += 256) {
        const float w = lin_w[t * C2 + cc];
        const float g = gamma[cc] * istd[cc];
        Wf[t * C2 + cc] = w * g;
        acc = fmaf(beta[cc] - mean[cc] * g, w, acc);
    }
    red[tid] = acc; __syncthreads();
    for (int o = 128; o; o >>= 1) { if (tid < o) red[tid] += red[tid + o]; __syncthreads(); }
    if (tid == 0) ct[t] = red[0] + lin_b[t];
}

// ---------------------------------------------------------------------------
// Emission logits from channel-major X2: block per timestep t, lane = batch.
// thread (b = tid&63, p = tid>>6) accumulates channels [p*256, p*256+256).
// ---------------------------------------------------------------------------
__global__ __launch_bounds__(256) void emit_logits(
    const float* __restrict__ X2, const float* __restrict__ Wf,
    const float* __restrict__ ct, float* __restrict__ E)
{
    __shared__ float ps[256 * TT];               // 17408 B partials
    const int t = blockIdx.x;
    const int tid = threadIdx.x;
    const int b = tid & 63, p = tid >> 6;
    const float* xb = X2 + (size_t)t * 64 + b;

    float acc[TT];
    #pragma unroll
    for (int k = 0; k < TT; k++) acc[k] = 0.f;

    for (int c0 = p * 256; c0 < p * 256 + 256; c0 += 4) {
        const float x0 = xb[(size_t)(c0 + 0) * NR];
        const float x1 = xb[(size_t)(c0 + 1) * NR];
        const float x2 = xb[(size_t)(c0 + 2) * NR];
        const float x3 = xb[(size_t)(c0 + 3) * NR];
        #pragma unroll
        for (int k = 0; k < TT; k++) {
            const float4 w = *(const float4*)&Wf[k * C2 + c0];   // wave-uniform
            acc[k] = fmaf(x0, w.x, fmaf(x1, w.y, fmaf(x2, w.z, fmaf(x3, w.w, acc[k]))));
        }
    }
    #pragma unroll
    for (int k = 0; k < TT; k++) ps[tid * TT + k] = acc[k];
    __syncthreads();
    if (tid < 64) {
        float* Er = E + ((size_t)tid * SL + t) * TT;
        #pragma unroll
        for (int k = 0; k < TT; k++) {
            float v = ct[k];
            #pragma unroll
            for (int q = 0; q < 4; q++) v += ps[(q * 64 + tid) * TT + k];
            Er[k] = v;
        }
    }
}

// ---------------------------------------------------------------------------
// CRF log-likelihood per batch element
// ---------------------------------------------------------------------------
__global__ __launch_bounds__(64) void crf_llh(
    const float* __restrict__ E, const int* __restrict__ mask,
    const int* __restrict__ labels, const float* __restrict__ startv,
    const float* __restrict__ endv, const float* __restrict__ trans,
    float* __restrict__ res)
{
    const int b = blockIdx.x, lane = threadIdx.x;
    __shared__ float tr[TT][TT];
    for (int i = lane; i < TT * TT; i += 64) tr[i / TT][i % TT] = trans[i];
    __syncthreads();
    const float* Eb = E + (size_t)b * SL * TT;
    const int j = (lane < TT) ? lane : 0;

    float alpha = -1e30f;
    if (lane < TT) alpha = startv[lane] + Eb[lane];

    float numacc = 0.f; int len = 0;
    for (int t = lane; t < SL; t += 64) {
        const int mt = mask[t * BS + b];
        len += (mt != 0);
        if (t >= 1 && mt) {
            const int yp = labels[(t - 1) * BS + b];
            const int yt = labels[t * BS + b];
            numacc += tr[yp][yt] + Eb[t * TT + yt];
        }
    }
    for (int off = 32; off; off >>= 1) {
        numacc += __shfl_xor(numacc, off);
        len += __shfl_xor(len, off);
    }

    for (int t = 1; t < SL; ++t) {
        const int mt = mask[t * BS + b];
        if (mt) {
            float av[TT];
            #pragma unroll
            for (int i = 0; i < TT; i++) av[i] = __shfl(alpha, i);
            const float e = (lane < TT) ? Eb[t * TT + lane] : 0.f;
            float mx = -1e30f;
            #pragma unroll
            for (int i = 0; i < TT; i++) mx = fmaxf(mx, av[i] + tr[i][j]);
            float ssum = 0.f;
            #pragma unroll
            for (int i = 0; i < TT; i++) ssum += expf(av[i] + tr[i][j] - mx);
            const float nxt = mx + logf(ssum) + e;
            if (lane < TT) alpha = nxt;
        }
    }
    float v = (lane < TT) ? alpha + endv[lane] : -1e30f;
    float mx = v;
    for (int off = 32; off; off >>= 1) mx = fmaxf(mx, __shfl_xor(mx, off));
    float se = (lane < TT) ? expf(v - mx) : 0.f;
    for (int off = 32; off; off >>= 1) se += __shfl_xor(se, off);
    const float Z = mx + logf(se);

    if (lane == 0) {
        const int y0 = labels[b];
        float num = startv[y0] + Eb[y0] + numacc;
        const int last = len - 1;
        const int yl = labels[last * BS + b];
        num += endv[yl];
        res[b] = num - Z;
    }
}

__global__ __launch_bounds__(64) void loss_reduce(const float* __restrict__ res, float* __restrict__ out)
{
    const int lane = threadIdx.x;
    float v = res[lane];
    for (int off = 32; off; off >>= 1) v += __shfl_xor(v, off);
    if (lane == 0) out[0] = -v;
}

// ---------------------------------------------------------------------------
// Viterbi per batch element
// ---------------------------------------------------------------------------
__global__ __launch_bounds__(64) void viterbi(
    const float* __restrict__ E, const int* __restrict__ mask,
    const float* __restrict__ startv, const float* __restrict__ endv,
    const float* __restrict__ trans, float* __restrict__ preds)
{
    const int b = blockIdx.x, lane = threadIdx.x;
    __shared__ float tr[TT][TT];
    __shared__ unsigned char bp[SL][TT];
    for (int i = lane; i < TT * TT; i += 64) tr[i / TT][i % TT] = trans[i];
    __syncthreads();
    const float* Eb = E + (size_t)b * SL * TT;
    const int j = (lane < TT) ? lane : 0;

    float score = (lane < TT) ? startv[lane] + Eb[lane] : -1e30f;
    for (int t = 1; t < SL; ++t) {
        float av[TT];
        #pragma unroll
        for (int i = 0; i < TT; i++) av[i] = __shfl(score, i);
        float best = -1e30f; int bi = 0;
        #pragma unroll
        for (int i = 0; i < TT; i++) {
            const float cand = av[i] + tr[i][j];
            if (cand > best) { best = cand; bi = i; }   // strict > => first max
        }
        const int mt = mask[t * BS + b];
        if (lane < TT) {
            bp[t][lane] = (unsigned char)bi;
            if (mt) score = best + Eb[t * TT + lane];
        }
    }
    float v = (lane < TT) ? score + endv[lane] : -1e30f;
    float mx = v;
    for (int off = 32; off; off >>= 1) mx = fmaxf(mx, __shfl_xor(mx, off));
    unsigned long long ball = __ballot(v == mx);
    const int last_tag = __ffsll(ball) - 1;
    __syncthreads();

    if (lane == 0) {
        int tag = last_tag;
        float* pb = preds + (size_t)b * SL;
        for (int t = SL - 1; t >= 1; --t) {
            const int mt = mask[t * BS + b];
            pb[t] = mt ? (float)tag : 0.f;
            if (mt) tag = bp[t][tag];
        }
        pb[0] = mask[b] ? (float)tag : 0.f;
    }
}

// ---------------------------------------------------------------------------
extern "C" void kernel_launch(void* const* d_in, const int* in_sizes, int n_in,
                              void* d_out, int out_size, void* d_ws, size_t ws_size,
                              hipStream_t stream)
{
    const float* word    = (const float*)d_in[0];
    const int*   mask    = (const int*)  d_in[1];
    const int*   labels  = (const int*)  d_in[2];
    const float* w_ih_f  = (const float*)d_in[3];
    const float* w_hh_f  = (const float*)d_in[4];
    const float* b_ih_f  = (const float*)d_in[5];
    const float* b_hh_f  = (const float*)d_in[6];
    const float* w_ih_b  = (const float*)d_in[7];
    const float* w_hh_b  = (const float*)d_in[8];
    const float* b_ih_b  = (const float*)d_in[9];
    const float* b_hh_b  = (const float*)d_in[10];
    const float* gamma   = (const float*)d_in[11];
    const float* beta    = (const float*)d_in[12];
    const float* lin_w   = (const float*)d_in[13];
    const float* lin_b   = (const float*)d_in[14];
    const float* c_start = (const float*)d_in[15];
    const float* c_end   = (const float*)d_in[16];
    const float* c_trans = (const float*)d_in[17];
    float* out = (float*)d_out;
    (void)in_sizes; (void)n_in; (void)out_size;

    char* ws = (char*)d_ws;
    size_t off = 0;
    auto alloc = [&](size_t bytes) {
        void* p = ws + off;
        off += (bytes + 255) & ~(size_t)255;
        return p;
    };
    float* XG_F  = (float*)alloc((size_t)NR * G4 * 4);          // 128 MB
    float* WPK_F = (float*)alloc((size_t)256 * 6144 * 4);       // 6.3 MB
    float* WPK_B = (float*)alloc((size_t)256 * 6144 * 4);       // 6.3 MB
    float* LOUT  = (float*)alloc((size_t)NR * C2 * 4);          // 64 MB channel-major
    float* HB_F  = (float*)alloc((size_t)2 * 512 * 64 * 4);     // 256 KB
    float* HB_B  = (float*)alloc((size_t)2 * 512 * 64 * 4);     // 256 KB
    int*   FLAGS = (int*)  alloc((size_t)2 * SL * NBLK * 4);    // 512 KB
    float* MEAN  = (float*)alloc(C2 * 4);
    float* ISTD  = (float*)alloc(C2 * 4);
    float* WF    = (float*)alloc(TT * C2 * 4);
    float* CT    = (float*)alloc(TT * 4);
    float* Ebuf  = (float*)alloc((size_t)BS * SL * TT * 4);
    float* RES   = (float*)alloc(BS * 4);
    float* XG_B  = (float*)alloc((size_t)NR * G4 * 4);          // 128 MB (merged only)
    const bool merged = (ws_size >= off);                       // ~336 MB needed
    if (!merged) XG_B = XG_F;                                   // sequential reuse

    init_flags<<<256, 512, 0, stream>>>(FLAGS);
    pack_whh_v3<<<256, 256, 0, stream>>>(w_hh_f, WPK_F);
    pack_whh_v3<<<256, 256, 0, stream>>>(w_hh_b, WPK_B);

    if (merged) {
        gemm_xg<<<dim3(NR / 128, G4 / 128), 256, 0, stream>>>(word, w_ih_f, b_ih_f, b_hh_f, XG_F);
        gemm_xg<<<dim3(NR / 128, G4 / 128), 256, 0, stream>>>(word, w_ih_b, b_ih_b, b_hh_b, XG_B);
        lstm_flag<<<2 * NBLK, 512, 0, stream>>>(XG_F, XG_B, WPK_F, WPK_B, HB_F, HB_B,
                                                FLAGS, FLAGS + SL * NBLK, LOUT, 0);
    } else {
        gemm_xg<<<dim3(NR / 128, G4 / 128), 256, 0, stream>>>(word, w_ih_f, b_ih_f, b_hh_f, XG_F);
        lstm_flag<<<NBLK, 512, 0, stream>>>(XG_F, XG_B, WPK_F, WPK_B, HB_F, HB_B,
                                            FLAGS, FLAGS + SL * NBLK, LOUT, 0);
        gemm_xg<<<dim3(NR / 128, G4 / 128), 256, 0, stream>>>(word, w_ih_b, b_ih_b, b_hh_b, XG_F);
        lstm_flag<<<NBLK, 512, 0, stream>>>(XG_F, XG_B, WPK_F, WPK_B, HB_F, HB_B,
                                            FLAGS, FLAGS + SL * NBLK, LOUT, 1);
    }

    bn_stats<<<C2, 256, 0, stream>>>(LOUT, MEAN, ISTD);
    fold_lin<<<TT, 256, 0, stream>>>(lin_w, lin_b, gamma, beta, MEAN, ISTD, WF, CT);
    emit_logits<<<SL, 256, 0, stream>>>(LOUT, WF, CT, Ebuf);

    crf_llh<<<BS, 64, 0, stream>>>(Ebuf, mask, labels, c_start, c_end, c_trans, RES);
    loss_reduce<<<1, 64, 0, stream>>>(RES, out);
    viterbi<<<BS, 64, 0, stream>>>(Ebuf, mask, c_start, c_end, c_trans, out + 1);
}